// Round 7
// baseline (526.450 us; speedup 1.0000x reference)
//
#include <hip/hip_runtime.h>
#include <hip/hip_fp16.h>
#include <cstdint>
#include <cstddef>

#define N_NODES  100000
#define N_EDGES  3200000
#define N_GRAPHS 64

#define BQBITS   9
#define BQ       512                      // nodes per bucket
#define NBUCK    196                      // ceil(100000/512)
#define TILE     4096                     // edges per pass-1 block
#define NBLK     782                      // ceil(3200000/4096)
#define POOL_SLICES 8

#define CAP      20480                    // LDS edge cap per bucket (Poisson(16384)+32 sigma)
#define NSTRIPE  8
#define STRIPE_W 12500

// ---------------- CSR build: bucketed 2-pass counting sort ----------------

__global__ void kp1_hist(const int* __restrict__ dst, int* __restrict__ gh, int ne) {
    __shared__ int h[NBUCK];
    for (int i = threadIdx.x; i < NBUCK; i += 256) h[i] = 0;
    __syncthreads();
    int base = blockIdx.x * TILE;
    for (int i = threadIdx.x; i < TILE; i += 256) {
        int e = base + i;
        if (e < ne) atomicAdd(&h[dst[e] >> BQBITS], 1);
    }
    __syncthreads();
    for (int i = threadIdx.x; i < NBUCK; i += 256) gh[i * NBLK + blockIdx.x] = h[i];
}

__global__ void kp1_scanA(int* __restrict__ gh, int* __restrict__ btotal) {
    int q = blockIdx.x;
    __shared__ int ts[256];
    int v[4];
    int tsum = 0;
#pragma unroll
    for (int u = 0; u < 4; ++u) {
        int idx = threadIdx.x * 4 + u;
        v[u] = (idx < NBLK) ? gh[q * NBLK + idx] : 0;
        tsum += v[u];
    }
    ts[threadIdx.x] = tsum;
    __syncthreads();
    for (int off = 1; off < 256; off <<= 1) {
        int t = (threadIdx.x >= off) ? ts[threadIdx.x - off] : 0;
        __syncthreads();
        ts[threadIdx.x] += t;
        __syncthreads();
    }
    int run = ts[threadIdx.x] - tsum;
#pragma unroll
    for (int u = 0; u < 4; ++u) {
        int idx = threadIdx.x * 4 + u;
        if (idx < NBLK) gh[q * NBLK + idx] = run;
        run += v[u];
    }
    if (threadIdx.x == 255) btotal[q] = ts[255];
}

__global__ void kp1_scanB(const int* __restrict__ btotal, int* __restrict__ bstart,
                          int* __restrict__ rs, int* __restrict__ perm) {
    __shared__ int s[256];
    int v = (threadIdx.x < NBUCK) ? btotal[threadIdx.x] : 0;
    s[threadIdx.x] = v;
    __syncthreads();
    for (int off = 1; off < 256; off <<= 1) {
        int t = (threadIdx.x >= off) ? s[threadIdx.x - off] : 0;
        __syncthreads();
        s[threadIdx.x] += t;
        __syncthreads();
    }
    if (threadIdx.x < NBUCK) bstart[threadIdx.x] = s[threadIdx.x] - v;
    if (threadIdx.x == 0) { bstart[NBUCK] = N_EDGES; rs[N_NODES] = N_EDGES; }
    if (threadIdx.x < 8) perm[N_EDGES + threadIdx.x] = 0;   // speculative-load pad
}

__global__ void kp1_scatter(const int* __restrict__ src, const int* __restrict__ dst,
                            const int* __restrict__ gh, const int* __restrict__ bstart,
                            unsigned* __restrict__ tmp, int ne) {
    __shared__ int lcnt[NBUCK];
    __shared__ int lbase[NBUCK];
    for (int i = threadIdx.x; i < NBUCK; i += 256) {
        lcnt[i] = 0;
        lbase[i] = bstart[i] + gh[i * NBLK + blockIdx.x];
    }
    __syncthreads();
    int base = blockIdx.x * TILE;
    for (int i = threadIdx.x; i < TILE; i += 256) {
        int e = base + i;
        if (e >= ne) continue;
        int d = dst[e], s = src[e];
        int q = d >> BQBITS;
        int r = atomicAdd(&lcnt[q], 1);
        tmp[lbase[q] + r] = ((unsigned)(d & (BQ - 1)) << 17) | (unsigned)s;
    }
}

// one block per bucket: node-histogram + scan -> rs; scatter into LDS;
// per-node insertion sort by src; coalesced write -> perm
__global__ void kp2(const unsigned* __restrict__ tmp, const int* __restrict__ bstart,
                    int* __restrict__ rs, int* __restrict__ perm) {
    int q = blockIdx.x;
    int beg = bstart[q], end = bstart[q + 1];
    int m = end - beg;
    __shared__ int cnt[BQ];
    __shared__ int lofs[BQ];
    __shared__ int fill[BQ];
    __shared__ int sed[CAP];
    if (threadIdx.x < BQ) { cnt[threadIdx.x] = 0; fill[threadIdx.x] = 0; }
    __syncthreads();
    for (int p = threadIdx.x; p < m; p += 1024)
        atomicAdd(&cnt[tmp[beg + p] >> 17], 1);
    __syncthreads();
    if (threadIdx.x < BQ) lofs[threadIdx.x] = cnt[threadIdx.x];
    __syncthreads();
    for (int off = 1; off < BQ; off <<= 1) {
        int t = 0;
        if (threadIdx.x < BQ && threadIdx.x >= off) t = lofs[threadIdx.x - off];
        __syncthreads();
        if (threadIdx.x < BQ) lofs[threadIdx.x] += t;   // inclusive
        __syncthreads();
    }
    if (threadIdx.x < BQ) {
        int node = q * BQ + threadIdx.x;
        if (node < N_NODES) rs[node] = beg + lofs[threadIdx.x] - cnt[threadIdx.x];
    }
    __syncthreads();
    if (m <= CAP) {
        for (int p = threadIdx.x; p < m; p += 1024) {
            unsigned w = tmp[beg + p];
            int dl = w >> 17;
            int s = w & 0x1FFFF;
            int r = atomicAdd(&fill[dl], 1);
            sed[lofs[dl] - cnt[dl] + r] = s;
        }
        __syncthreads();
        if (threadIdx.x < BQ) {
            int p0 = lofs[threadIdx.x] - cnt[threadIdx.x];
            int c = cnt[threadIdx.x];
            for (int i = p0 + 1; i < p0 + c; ++i) {
                int v = sed[i];
                int j = i - 1;
                while (j >= p0 && sed[j] > v) { sed[j + 1] = sed[j]; --j; }
                sed[j + 1] = v;
            }
        }
        __syncthreads();
        for (int p = threadIdx.x; p < m; p += 1024) perm[beg + p] = sed[p];
    } else {
        // fallback (statistically unreachable): unsorted fill, still correct
        for (int p = threadIdx.x; p < m; p += 1024) {
            unsigned w = tmp[beg + p];
            int dl = w >> 17;
            int s = w & 0x1FFFF;
            int r = atomicAdd(&fill[dl], 1);
            perm[beg + lofs[dl] - cnt[dl] + r] = s;
        }
    }
}

// ---------------- transforms ----------------

// y1(half) = x @ W1l ; s1(f32) = x @ W1r + b1      (64 -> 16)
__global__ void k_t1(const float* __restrict__ x, const float* __restrict__ W1l,
                     const float* __restrict__ W1r, const float* __restrict__ b1,
                     __half* __restrict__ y1, float* __restrict__ s1, int n) {
    __shared__ float wl[64 * 16], wr[64 * 16], bb[16];
    for (int i = threadIdx.x; i < 64 * 16; i += blockDim.x) { wl[i] = W1l[i]; wr[i] = W1r[i]; }
    if (threadIdx.x < 16) bb[threadIdx.x] = b1[threadIdx.x];
    __syncthreads();
    int node = blockIdx.x * blockDim.x + threadIdx.x;
    if (node >= n) return;
    const float4* xr = reinterpret_cast<const float4*>(x + (size_t)node * 64);
    float accl[16], accr[16];
#pragma unroll
    for (int j = 0; j < 16; ++j) { accl[j] = 0.f; accr[j] = 0.f; }
#pragma unroll
    for (int q = 0; q < 16; ++q) {
        float4 v = xr[q];
        float xs[4] = {v.x, v.y, v.z, v.w};
#pragma unroll
        for (int u = 0; u < 4; ++u) {
            int k = q * 4 + u;
            float xv = xs[u];
#pragma unroll
            for (int j = 0; j < 16; ++j) {
                accl[j] += xv * wl[k * 16 + j];
                accr[j] += xv * wr[k * 16 + j];
            }
        }
    }
    alignas(16) __half yh[16];
#pragma unroll
    for (int j = 0; j < 16; ++j) yh[j] = __float2half(accl[j]);
    uint4* y4 = reinterpret_cast<uint4*>(y1 + (size_t)node * 16);
    const uint4* yv = reinterpret_cast<const uint4*>(yh);
    y4[0] = yv[0]; y4[1] = yv[1];
    float4* s4 = reinterpret_cast<float4*>(s1 + (size_t)node * 16);
#pragma unroll
    for (int q = 0; q < 4; ++q)
        s4[q] = make_float4(accr[q*4+0] + bb[q*4+0], accr[q*4+1] + bb[q*4+1],
                            accr[q*4+2] + bb[q*4+2], accr[q*4+3] + bb[q*4+3]);
}

// h2(f32) = mean2 @ W2l + h(half) @ W2r + b2      (16 -> 32)
__global__ void k_t2(const float* __restrict__ mean2, const __half* __restrict__ h,
                     const float* __restrict__ W2l, const float* __restrict__ W2r,
                     const float* __restrict__ b2, float* __restrict__ h2, int n) {
    __shared__ float wl[16 * 32], wr[16 * 32], bb[32];
    for (int i = threadIdx.x; i < 16 * 32; i += blockDim.x) { wl[i] = W2l[i]; wr[i] = W2r[i]; }
    if (threadIdx.x < 32) bb[threadIdx.x] = b2[threadIdx.x];
    __syncthreads();
    int node = blockIdx.x * blockDim.x + threadIdx.x;
    if (node >= n) return;
    float m[16], hh[16];
    const float4* m4 = reinterpret_cast<const float4*>(mean2 + (size_t)node * 16);
#pragma unroll
    for (int q = 0; q < 4; ++q) {
        float4 a = m4[q];
        m[q*4+0]=a.x; m[q*4+1]=a.y; m[q*4+2]=a.z; m[q*4+3]=a.w;
    }
    alignas(16) __half hv[16];
    const uint4* hp = reinterpret_cast<const uint4*>(h + (size_t)node * 16);
    uint4* hvp = reinterpret_cast<uint4*>(hv);
    hvp[0] = hp[0]; hvp[1] = hp[1];
#pragma unroll
    for (int k = 0; k < 16; ++k) hh[k] = __half2float(hv[k]);
    float acc[32];
#pragma unroll
    for (int j = 0; j < 32; ++j) acc[j] = bb[j];
#pragma unroll
    for (int k = 0; k < 16; ++k) {
#pragma unroll
        for (int j = 0; j < 32; ++j)
            acc[j] += m[k] * wl[k * 32 + j] + hh[k] * wr[k * 32 + j];
    }
    float4* o4 = reinterpret_cast<float4*>(h2 + (size_t)node * 32);
#pragma unroll
    for (int q = 0; q < 8; ++q)
        o4[q] = make_float4(acc[q*4+0], acc[q*4+1], acc[q*4+2], acc[q*4+3]);
}

// z = relu(h2); y3(half, stride 24) = z @ W3l ; s3(f32) = z @ W3r + b3   (32 -> 21)
__global__ void k_t3(const float* __restrict__ h2, const float* __restrict__ W3l,
                     const float* __restrict__ W3r, const float* __restrict__ b3,
                     __half* __restrict__ y3, float* __restrict__ s3, int n) {
    __shared__ float wl[32 * 21], wr[32 * 21], bb[21];
    for (int i = threadIdx.x; i < 32 * 21; i += blockDim.x) { wl[i] = W3l[i]; wr[i] = W3r[i]; }
    if (threadIdx.x < 21) bb[threadIdx.x] = b3[threadIdx.x];
    __syncthreads();
    int node = blockIdx.x * blockDim.x + threadIdx.x;
    if (node >= n) return;
    float z[32];
    const float4* h4 = reinterpret_cast<const float4*>(h2 + (size_t)node * 32);
#pragma unroll
    for (int q = 0; q < 8; ++q) {
        float4 v = h4[q];
        z[q*4+0] = fmaxf(v.x, 0.f); z[q*4+1] = fmaxf(v.y, 0.f);
        z[q*4+2] = fmaxf(v.z, 0.f); z[q*4+3] = fmaxf(v.w, 0.f);
    }
    float a[21], c[21];
#pragma unroll
    for (int j = 0; j < 21; ++j) { a[j] = 0.f; c[j] = bb[j]; }
#pragma unroll
    for (int k = 0; k < 32; ++k) {
#pragma unroll
        for (int j = 0; j < 21; ++j) {
            a[j] += z[k] * wl[k * 21 + j];
            c[j] += z[k] * wr[k * 21 + j];
        }
    }
    alignas(16) __half yh[24];
#pragma unroll
    for (int j = 0; j < 21; ++j) yh[j] = __float2half(a[j]);
    yh[21] = __half(0.f); yh[22] = __half(0.f); yh[23] = __half(0.f);
    uint4* yp = reinterpret_cast<uint4*>(y3 + (size_t)node * 24);
    const uint4* yv = reinterpret_cast<const uint4*>(yh);
    yp[0] = yv[0]; yp[1] = yv[1]; yp[2] = yv[2];
    float* so = s3 + (size_t)node * 21;
#pragma unroll
    for (int j = 0; j < 21; ++j) so[j] = c[j];
}

// ------- persistent stripe-paced aggregation (sorted adjacency, fp16 table) -------

template <int GSZ, int F, int STRIDE, int NCH, bool RELU, bool SELF, bool OUT_HALF>
__global__ __launch_bounds__(256, 8)
void k_aggp(const __half* __restrict__ y, const int* __restrict__ rs,
            const int* __restrict__ perm, const float* __restrict__ self,
            void* __restrict__ outp) {
    int tid = blockIdx.x * 256 + threadIdx.x;
    int group = tid / GSZ;
    int f = tid % GSZ;
    int nbase = group * NCH;
    int fc = (f < F) ? f : 0;

    int eptr[NCH], eend[NCH];
    float acc[NCH], dinv[NCH];
#pragma unroll
    for (int i = 0; i < NCH; ++i) {
        int n = nbase + i;
        int b = 0, e = 0;
        if (n < N_NODES) { b = rs[n]; e = rs[n + 1]; }
        eptr[i] = b; eend[i] = e; acc[i] = 0.f;
        dinv[i] = 1.0f / fmaxf((float)(e - b), 1.0f);
    }

#pragma unroll 1
    for (int s = 0; s < NSTRIPE; ++s) {
        int limit = (s == NSTRIPE - 1) ? 0x7fffffff : (s + 1) * STRIPE_W;
#pragma unroll
        for (int i = 0; i < NCH; ++i) {
            int e = eptr[i];
            int en = eend[i];
            while (e < en) {
                int s0 = __builtin_nontemporal_load(&perm[e]);
                int s1 = __builtin_nontemporal_load(&perm[e + 1]);
                int s2 = __builtin_nontemporal_load(&perm[e + 2]);
                int s3 = __builtin_nontemporal_load(&perm[e + 3]);
                float v0 = __half2float(y[(size_t)s0 * STRIDE + fc]);
                float v1 = __half2float(y[(size_t)s1 * STRIDE + fc]);
                float v2 = __half2float(y[(size_t)s2 * STRIDE + fc]);
                float v3 = __half2float(y[(size_t)s3 * STRIDE + fc]);
                bool m0 = (s0 < limit);
                bool m1 = (e + 1 < en) && (s1 < limit);
                bool m2 = (e + 2 < en) && (s2 < limit);
                bool m3 = (e + 3 < en) && (s3 < limit);
                acc[i] += (m0 ? v0 : 0.f) + (m1 ? v1 : 0.f)
                        + (m2 ? v2 : 0.f) + (m3 ? v3 : 0.f);
                int c = (int)m0 + (int)m1 + (int)m2 + (int)m3;
                e += c;
                if (c < 4) break;
            }
            eptr[i] = e;
        }
    }

#pragma unroll
    for (int i = 0; i < NCH; ++i) {
        int n = nbase + i;
        if (n >= N_NODES || f >= F) continue;
        float v = acc[i] * dinv[i];
        if (SELF) v += __builtin_nontemporal_load(&self[(size_t)n * F + f]);
        if (RELU) v = fmaxf(v, 0.f);
        if constexpr (OUT_HALF) {
            __half hv = __float2half(v);
            unsigned short bits = *reinterpret_cast<unsigned short*>(&hv);
            __builtin_nontemporal_store(bits, (unsigned short*)outp + (size_t)n * F + f);
        } else {
            __builtin_nontemporal_store(v, (float*)outp + (size_t)n * F + f);
        }
    }
}

// ---------------- pooling + classifier ----------------

__device__ __forceinline__ int lowerb(const int* a, int n, int key) {
    int lo = 0, hi = n;
    while (lo < hi) { int mid = (lo + hi) >> 1; if (a[mid] < key) lo = mid + 1; else hi = mid; }
    return lo;
}

__global__ void k_pool(const float* __restrict__ h2, const int* __restrict__ batch,
                       float* __restrict__ gsum, float* __restrict__ gcnt, int n) {
    int g = blockIdx.x / POOL_SLICES;
    int slice = blockIdx.x - g * POOL_SLICES;
    __shared__ int sbeg, send;
    if (threadIdx.x == 0) { sbeg = lowerb(batch, n, g); send = lowerb(batch, n, g + 1); }
    __syncthreads();
    int beg = sbeg, end = send;
    int f = threadIdx.x & 31;
    int r = threadIdx.x >> 5;   // 8 row-groups
    float acc = 0.f;
    for (int i = beg + slice * 8 + r; i < end; i += POOL_SLICES * 8)
        acc += h2[(size_t)i * 32 + f];
    __shared__ float red[256];
    red[threadIdx.x] = acc;
    __syncthreads();
    if (r == 0) {
        float s = 0.f;
#pragma unroll
        for (int q = 0; q < 8; ++q) s += red[q * 32 + f];
        atomicAdd(&gsum[g * 32 + f], s);
    }
    if (slice == 0 && threadIdx.x == 0) gcnt[g] = (float)(end - beg);
}

__global__ void k_cls(const float* __restrict__ gsum, const float* __restrict__ gcnt,
                      const float* __restrict__ Wc, const float* __restrict__ bc,
                      float* __restrict__ outp) {
    int t = threadIdx.x;
    if (t >= N_GRAPHS * 10) return;
    int g = t / 10, c = t - g * 10;
    float cv = fmaxf(gcnt[g], 1.f);
    float acc = bc[c];
#pragma unroll
    for (int k = 0; k < 32; ++k) acc += (gsum[g * 32 + k] / cv) * Wc[k * 10 + c];
    outp[g * 10 + c] = acc;
}

// ---------------- launch ----------------

extern "C" void kernel_launch(void* const* d_in, const int* in_sizes, int n_in,
                              void* d_out, int out_size, void* d_ws, size_t ws_size,
                              hipStream_t stream) {
    const float* x    = (const float*)d_in[0];
    const int*   ei   = (const int*)d_in[1];
    const int*   batch= (const int*)d_in[2];
    const float* W1l  = (const float*)d_in[3];
    const float* b1   = (const float*)d_in[4];
    const float* W1r  = (const float*)d_in[5];
    const float* W2l  = (const float*)d_in[6];
    const float* b2   = (const float*)d_in[7];
    const float* W2r  = (const float*)d_in[8];
    const float* W3l  = (const float*)d_in[9];
    const float* b3   = (const float*)d_in[10];
    const float* W3r  = (const float*)d_in[11];
    const float* Wc   = (const float*)d_in[12];
    const float* bc   = (const float*)d_in[13];
    float* out = (float*)d_out;

    char* ws = (char*)d_ws;
    size_t off = 0;
    auto alloc = [&](size_t bytes) { size_t o = off; off += (bytes + 255) & ~(size_t)255; return o; };

    int*    rs    = (int*)(ws + alloc((size_t)(N_NODES + 1) * 4));
    int*    perm  = (int*)(ws + alloc((size_t)(N_EDGES + 8) * 4));
    int*    gh    = (int*)(ws + alloc((size_t)NBUCK * NBLK * 4));
    int*    btotal= (int*)(ws + alloc(256 * 4));
    int*    bstart= (int*)(ws + alloc(260 * 4));
    __half* y1    = (__half*)(ws + alloc((size_t)N_NODES * 16 * 2));
    float*  s1    = (float*)(ws + alloc((size_t)N_NODES * 16 * 4));
    __half* h     = (__half*)(ws + alloc((size_t)N_NODES * 16 * 2));
    float*  mean2 = (float*)(ws + alloc((size_t)N_NODES * 16 * 4));
    float*  h2    = (float*)(ws + alloc((size_t)N_NODES * 32 * 4));
    __half* y3    = (__half*)(ws + alloc((size_t)N_NODES * 24 * 2));
    float*  s3    = (float*)(ws + alloc((size_t)N_NODES * 21 * 4));
    float*  gsum  = (float*)(ws + alloc((size_t)N_GRAPHS * 32 * 4));
    float*  gcnt  = (float*)(ws + alloc((size_t)N_GRAPHS * 4));

    // tmp (12.8 MB) aliases h2 (12.8 MB): tmp dead before k_t2 writes h2
    unsigned* tmp = (unsigned*)h2;

    const int* src = ei;
    const int* dst = ei + N_EDGES;

    int nb = (N_NODES + 255) / 256;   // 391

    // persistent-agg grids (all blocks resident: <= 8 blocks/CU on 256 CUs)
    const int GRID16 = (N_NODES / 4 * 16 + 255) / 256;        // 1563 blocks (GSZ16, NCH4)
    const int GRID21 = (((N_NODES + 6) / 7) * 32 + 255) / 256; // 1786 blocks (GSZ32, NCH7)

    // CSR build (bucketed 2-pass counting sort, no global atomics, src-sorted lists)
    kp1_hist   <<<NBLK, 256, 0, stream>>>(dst, gh, N_EDGES);
    kp1_scanA  <<<NBUCK, 256, 0, stream>>>(gh, btotal);
    kp1_scanB  <<<1, 256, 0, stream>>>(btotal, bstart, rs, perm);
    kp1_scatter<<<NBLK, 256, 0, stream>>>(src, dst, gh, bstart, tmp, N_EDGES);
    kp2        <<<NBUCK, 1024, 0, stream>>>(tmp, bstart, rs, perm);

    // layer 1: transform-first (64->16), stripe-paced aggregate, +self, relu -> h (fp16)
    k_t1<<<nb, 256, 0, stream>>>(x, W1l, W1r, b1, y1, s1, N_NODES);
    k_aggp<16, 16, 16, 4, true, true, true>
        <<<GRID16, 256, 0, stream>>>(y1, rs, perm, s1, h);

    // layer 2: stripe-paced aggregate-first -> mean2 (f32), then 16->32
    k_aggp<16, 16, 16, 4, false, false, false>
        <<<GRID16, 256, 0, stream>>>(h, rs, perm, nullptr, mean2);
    k_t2<<<nb, 256, 0, stream>>>(mean2, h, W2l, W2r, b2, h2, N_NODES);

    // layer 3: transform-first on relu(h2) (32->21), stripe-paced aggregate, +self
    k_t3<<<nb, 256, 0, stream>>>(h2, W3l, W3r, b3, y3, s3, N_NODES);
    k_aggp<32, 21, 24, 7, false, true, false>
        <<<GRID21, 256, 0, stream>>>(y3, rs, perm, s3, out + N_GRAPHS * 10);

    // pooling over h2 (pre-relu, zero gsum first) + classifier
    hipMemsetAsync(gsum, 0, (size_t)N_GRAPHS * 32 * 4, stream);
    k_pool<<<N_GRAPHS * POOL_SLICES, 256, 0, stream>>>(h2, batch, gsum, gcnt, N_NODES);
    k_cls<<<1, 640, 0, stream>>>(gsum, gcnt, Wc, bc, out);
}

// Round 8
// 454.379 us; speedup vs baseline: 1.1586x; 1.1586x over previous
//
#include <hip/hip_runtime.h>
#include <hip/hip_fp16.h>
#include <cstdint>
#include <cstddef>

#define N_NODES  100000
#define N_EDGES  3200000
#define N_GRAPHS 64

#define BQBITS   9
#define BQ       512                      // nodes per bucket
#define NBUCK    196                      // ceil(100000/512)
#define TILE     4096                     // edges per pass-1 block
#define NBLK     782                      // ceil(3200000/4096)
#define POOL_SLICES 8

#define NSTR     7                        // src stripes (16384 nodes each)
#define SSHIFT   14
#define NKEY     (BQ * NSTR)              // 3584 (node-local, stripe) keys

// ---------------- CSR build: bucketed 2-pass counting sort ----------------

__global__ void kp1_hist(const int* __restrict__ dst, int* __restrict__ gh, int ne) {
    __shared__ int h[NBUCK];
    for (int i = threadIdx.x; i < NBUCK; i += 256) h[i] = 0;
    __syncthreads();
    int base = blockIdx.x * TILE;
    for (int i = threadIdx.x; i < TILE; i += 256) {
        int e = base + i;
        if (e < ne) atomicAdd(&h[dst[e] >> BQBITS], 1);
    }
    __syncthreads();
    for (int i = threadIdx.x; i < NBUCK; i += 256) gh[i * NBLK + blockIdx.x] = h[i];
}

__global__ void kp1_scanA(int* __restrict__ gh, int* __restrict__ btotal) {
    int q = blockIdx.x;
    __shared__ int ts[256];
    int v[4];
    int tsum = 0;
#pragma unroll
    for (int u = 0; u < 4; ++u) {
        int idx = threadIdx.x * 4 + u;
        v[u] = (idx < NBLK) ? gh[q * NBLK + idx] : 0;
        tsum += v[u];
    }
    ts[threadIdx.x] = tsum;
    __syncthreads();
    for (int off = 1; off < 256; off <<= 1) {
        int t = (threadIdx.x >= off) ? ts[threadIdx.x - off] : 0;
        __syncthreads();
        ts[threadIdx.x] += t;
        __syncthreads();
    }
    int run = ts[threadIdx.x] - tsum;
#pragma unroll
    for (int u = 0; u < 4; ++u) {
        int idx = threadIdx.x * 4 + u;
        if (idx < NBLK) gh[q * NBLK + idx] = run;
        run += v[u];
    }
    if (threadIdx.x == 255) btotal[q] = ts[255];
}

__global__ void kp1_scanB(const int* __restrict__ btotal, int* __restrict__ bstart,
                          int* __restrict__ rs, int* __restrict__ perm) {
    __shared__ int s[256];
    int v = (threadIdx.x < NBUCK) ? btotal[threadIdx.x] : 0;
    s[threadIdx.x] = v;
    __syncthreads();
    for (int off = 1; off < 256; off <<= 1) {
        int t = (threadIdx.x >= off) ? s[threadIdx.x - off] : 0;
        __syncthreads();
        s[threadIdx.x] += t;
        __syncthreads();
    }
    if (threadIdx.x < NBUCK) bstart[threadIdx.x] = s[threadIdx.x] - v;
    if (threadIdx.x == 0) { bstart[NBUCK] = N_EDGES; rs[N_NODES] = N_EDGES; }
    if (threadIdx.x < 8) perm[N_EDGES + threadIdx.x] = 0;   // speculative-load pad
}

__global__ void kp1_scatter(const int* __restrict__ src, const int* __restrict__ dst,
                            const int* __restrict__ gh, const int* __restrict__ bstart,
                            unsigned* __restrict__ tmp, int ne) {
    __shared__ int lcnt[NBUCK];
    __shared__ int lbase[NBUCK];
    for (int i = threadIdx.x; i < NBUCK; i += 256) {
        lcnt[i] = 0;
        lbase[i] = bstart[i] + gh[i * NBLK + blockIdx.x];
    }
    __syncthreads();
    int base = blockIdx.x * TILE;
    for (int i = threadIdx.x; i < TILE; i += 256) {
        int e = base + i;
        if (e >= ne) continue;
        int d = dst[e], s = src[e];
        int q = d >> BQBITS;
        int r = atomicAdd(&lcnt[q], 1);
        tmp[lbase[q] + r] = ((unsigned)(d & (BQ - 1)) << 17) | (unsigned)s;
    }
}

// one block per bucket: (node,stripe) counting sort; emits rs, perm (stripe-grouped
// per node) and packed per-(node,stripe) u8 counts in deltas
__global__ void kp2(const unsigned* __restrict__ tmp, const int* __restrict__ bstart,
                    int* __restrict__ rs, int* __restrict__ perm,
                    unsigned long long* __restrict__ deltas) {
    int q = blockIdx.x;
    int beg = bstart[q], end = bstart[q + 1];
    int m = end - beg;
    __shared__ int cnt[NKEY];
    __shared__ int lofs[NKEY];
    __shared__ int fill[NKEY];
    __shared__ int ts[1024];
    for (int i = threadIdx.x; i < NKEY; i += 1024) { cnt[i] = 0; fill[i] = 0; }
    __syncthreads();
    for (int p = threadIdx.x; p < m; p += 1024) {
        unsigned w = tmp[beg + p];
        int dl = w >> 17;
        int s = w & 0x1FFFF;
        atomicAdd(&cnt[dl * NSTR + (s >> SSHIFT)], 1);
    }
    __syncthreads();
    // exclusive scan over NKEY (4 contiguous per thread)
    int b4 = threadIdx.x * 4;
    int v0 = (b4 + 0 < NKEY) ? cnt[b4 + 0] : 0;
    int v1 = (b4 + 1 < NKEY) ? cnt[b4 + 1] : 0;
    int v2 = (b4 + 2 < NKEY) ? cnt[b4 + 2] : 0;
    int v3 = (b4 + 3 < NKEY) ? cnt[b4 + 3] : 0;
    int tsum = v0 + v1 + v2 + v3;
    ts[threadIdx.x] = tsum;
    __syncthreads();
    for (int off = 1; off < 1024; off <<= 1) {
        int t = (threadIdx.x >= off) ? ts[threadIdx.x - off] : 0;
        __syncthreads();
        ts[threadIdx.x] += t;
        __syncthreads();
    }
    int run = ts[threadIdx.x] - tsum;
    if (b4 + 0 < NKEY) lofs[b4 + 0] = run;
    if (b4 + 1 < NKEY) lofs[b4 + 1] = run + v0;
    if (b4 + 2 < NKEY) lofs[b4 + 2] = run + v0 + v1;
    if (b4 + 3 < NKEY) lofs[b4 + 3] = run + v0 + v1 + v2;
    __syncthreads();
    if (threadIdx.x < BQ) {
        int node = q * BQ + threadIdx.x;
        if (node < N_NODES) {
            rs[node] = beg + lofs[threadIdx.x * NSTR];
            unsigned long long d = 0;
#pragma unroll
            for (int st = 0; st < NSTR; ++st)
                d |= (unsigned long long)(unsigned char)cnt[threadIdx.x * NSTR + st]
                     << (8 * st);
            deltas[node] = d;
        }
    }
    __syncthreads();
    for (int p = threadIdx.x; p < m; p += 1024) {
        unsigned w = tmp[beg + p];
        int dl = w >> 17;
        int s = w & 0x1FFFF;
        int key = dl * NSTR + (s >> SSHIFT);
        int r = atomicAdd(&fill[key], 1);
        perm[beg + lofs[key] + r] = s;
    }
}

// ---------------- transforms ----------------

// y1(half) = x @ W1l ; s1(f32) = x @ W1r + b1      (64 -> 16)
__global__ void k_t1(const float* __restrict__ x, const float* __restrict__ W1l,
                     const float* __restrict__ W1r, const float* __restrict__ b1,
                     __half* __restrict__ y1, float* __restrict__ s1, int n) {
    __shared__ float wl[64 * 16], wr[64 * 16], bb[16];
    for (int i = threadIdx.x; i < 64 * 16; i += blockDim.x) { wl[i] = W1l[i]; wr[i] = W1r[i]; }
    if (threadIdx.x < 16) bb[threadIdx.x] = b1[threadIdx.x];
    __syncthreads();
    int node = blockIdx.x * blockDim.x + threadIdx.x;
    if (node >= n) return;
    const float4* xr = reinterpret_cast<const float4*>(x + (size_t)node * 64);
    float accl[16], accr[16];
#pragma unroll
    for (int j = 0; j < 16; ++j) { accl[j] = 0.f; accr[j] = 0.f; }
#pragma unroll
    for (int q = 0; q < 16; ++q) {
        float4 v = xr[q];
        float xs[4] = {v.x, v.y, v.z, v.w};
#pragma unroll
        for (int u = 0; u < 4; ++u) {
            int k = q * 4 + u;
            float xv = xs[u];
#pragma unroll
            for (int j = 0; j < 16; ++j) {
                accl[j] += xv * wl[k * 16 + j];
                accr[j] += xv * wr[k * 16 + j];
            }
        }
    }
    alignas(16) __half yh[16];
#pragma unroll
    for (int j = 0; j < 16; ++j) yh[j] = __float2half(accl[j]);
    uint4* y4 = reinterpret_cast<uint4*>(y1 + (size_t)node * 16);
    const uint4* yv = reinterpret_cast<const uint4*>(yh);
    y4[0] = yv[0]; y4[1] = yv[1];
    float4* s4 = reinterpret_cast<float4*>(s1 + (size_t)node * 16);
#pragma unroll
    for (int q = 0; q < 4; ++q)
        s4[q] = make_float4(accr[q*4+0] + bb[q*4+0], accr[q*4+1] + bb[q*4+1],
                            accr[q*4+2] + bb[q*4+2], accr[q*4+3] + bb[q*4+3]);
}

// h2(f32) = mean2 @ W2l + h(half) @ W2r + b2      (16 -> 32)
__global__ void k_t2(const float* __restrict__ mean2, const __half* __restrict__ h,
                     const float* __restrict__ W2l, const float* __restrict__ W2r,
                     const float* __restrict__ b2, float* __restrict__ h2, int n) {
    __shared__ float wl[16 * 32], wr[16 * 32], bb[32];
    for (int i = threadIdx.x; i < 16 * 32; i += blockDim.x) { wl[i] = W2l[i]; wr[i] = W2r[i]; }
    if (threadIdx.x < 32) bb[threadIdx.x] = b2[threadIdx.x];
    __syncthreads();
    int node = blockIdx.x * blockDim.x + threadIdx.x;
    if (node >= n) return;
    float m[16], hh[16];
    const float4* m4 = reinterpret_cast<const float4*>(mean2 + (size_t)node * 16);
#pragma unroll
    for (int q = 0; q < 4; ++q) {
        float4 a = m4[q];
        m[q*4+0]=a.x; m[q*4+1]=a.y; m[q*4+2]=a.z; m[q*4+3]=a.w;
    }
    alignas(16) __half hv[16];
    const uint4* hp = reinterpret_cast<const uint4*>(h + (size_t)node * 16);
    uint4* hvp = reinterpret_cast<uint4*>(hv);
    hvp[0] = hp[0]; hvp[1] = hp[1];
#pragma unroll
    for (int k = 0; k < 16; ++k) hh[k] = __half2float(hv[k]);
    float acc[32];
#pragma unroll
    for (int j = 0; j < 32; ++j) acc[j] = bb[j];
#pragma unroll
    for (int k = 0; k < 16; ++k) {
#pragma unroll
        for (int j = 0; j < 32; ++j)
            acc[j] += m[k] * wl[k * 32 + j] + hh[k] * wr[k * 32 + j];
    }
    float4* o4 = reinterpret_cast<float4*>(h2 + (size_t)node * 32);
#pragma unroll
    for (int q = 0; q < 8; ++q)
        o4[q] = make_float4(acc[q*4+0], acc[q*4+1], acc[q*4+2], acc[q*4+3]);
}

// z = relu(h2); y3(half, stride 24) = z @ W3l ; s3(f32) = z @ W3r + b3   (32 -> 21)
__global__ void k_t3(const float* __restrict__ h2, const float* __restrict__ W3l,
                     const float* __restrict__ W3r, const float* __restrict__ b3,
                     __half* __restrict__ y3, float* __restrict__ s3, int n) {
    __shared__ float wl[32 * 21], wr[32 * 21], bb[21];
    for (int i = threadIdx.x; i < 32 * 21; i += blockDim.x) { wl[i] = W3l[i]; wr[i] = W3r[i]; }
    if (threadIdx.x < 21) bb[threadIdx.x] = b3[threadIdx.x];
    __syncthreads();
    int node = blockIdx.x * blockDim.x + threadIdx.x;
    if (node >= n) return;
    float z[32];
    const float4* h4 = reinterpret_cast<const float4*>(h2 + (size_t)node * 32);
#pragma unroll
    for (int q = 0; q < 8; ++q) {
        float4 v = h4[q];
        z[q*4+0] = fmaxf(v.x, 0.f); z[q*4+1] = fmaxf(v.y, 0.f);
        z[q*4+2] = fmaxf(v.z, 0.f); z[q*4+3] = fmaxf(v.w, 0.f);
    }
    float a[21], c[21];
#pragma unroll
    for (int j = 0; j < 21; ++j) { a[j] = 0.f; c[j] = bb[j]; }
#pragma unroll
    for (int k = 0; k < 32; ++k) {
#pragma unroll
        for (int j = 0; j < 21; ++j) {
            a[j] += z[k] * wl[k * 21 + j];
            c[j] += z[k] * wr[k * 21 + j];
        }
    }
    alignas(16) __half yh[24];
#pragma unroll
    for (int j = 0; j < 21; ++j) yh[j] = __float2half(a[j]);
    yh[21] = __half(0.f); yh[22] = __half(0.f); yh[23] = __half(0.f);
    uint4* yp = reinterpret_cast<uint4*>(y3 + (size_t)node * 24);
    const uint4* yv = reinterpret_cast<const uint4*>(yh);
    yp[0] = yv[0]; yp[1] = yv[1]; yp[2] = yv[2];
    float* so = s3 + (size_t)node * 21;
#pragma unroll
    for (int j = 0; j < 21; ++j) so[j] = c[j];
}

// ---- aggregation: stripe-paced gather (exact per-stripe counts, fp16 table) ----

template <int F, int STRIDE, bool RELU, bool SELF, bool OUT_HALF>
__global__ void k_agg(const __half* __restrict__ y, const int* __restrict__ rs,
                      const int* __restrict__ perm,
                      const unsigned long long* __restrict__ deltas,
                      const float* __restrict__ self,
                      void* __restrict__ outp, int n_nodes) {
    int t = blockIdx.x * blockDim.x + threadIdx.x;
    int node = t / F;
    int f = t - node * F;
    if (node >= n_nodes) return;
    int beg = rs[node], end = rs[node + 1];
    unsigned long long dd = deltas[node];
    float acc = 0.f;
    int e = beg;
#pragma unroll 1
    for (int st = 0; st < NSTR; ++st) {
        int c = (int)((dd >> (8 * st)) & 255ull);
        int ee = e + c;
        while (e < ee) {
            bool m1 = (e + 1 < ee), m2 = (e + 2 < ee), m3 = (e + 3 < ee);
            int s0 = __builtin_nontemporal_load(&perm[e]);
            int s1 = __builtin_nontemporal_load(&perm[e + 1]);
            int s2 = __builtin_nontemporal_load(&perm[e + 2]);
            int s3 = __builtin_nontemporal_load(&perm[e + 3]);
            float v0 = 0.f, v1 = 0.f, v2 = 0.f, v3 = 0.f;
            v0 = __half2float(y[(size_t)s0 * STRIDE + f]);
            if (m1) v1 = __half2float(y[(size_t)s1 * STRIDE + f]);
            if (m2) v2 = __half2float(y[(size_t)s2 * STRIDE + f]);
            if (m3) v3 = __half2float(y[(size_t)s3 * STRIDE + f]);
            acc += (v0 + v1) + (v2 + v3);
            e += 4;
        }
        e = ee;
    }
    float v = acc / fmaxf((float)(end - beg), 1.0f);
    if (SELF) v += __builtin_nontemporal_load(&self[(size_t)node * F + f]);
    if (RELU) v = fmaxf(v, 0.f);
    if constexpr (OUT_HALF) {
        __half hv = __float2half(v);
        unsigned short bits = *reinterpret_cast<unsigned short*>(&hv);
        __builtin_nontemporal_store(bits, (unsigned short*)outp + (size_t)node * F + f);
    } else {
        __builtin_nontemporal_store(v, (float*)outp + (size_t)node * F + f);
    }
}

// ---------------- pooling + classifier ----------------

__device__ __forceinline__ int lowerb(const int* a, int n, int key) {
    int lo = 0, hi = n;
    while (lo < hi) { int mid = (lo + hi) >> 1; if (a[mid] < key) lo = mid + 1; else hi = mid; }
    return lo;
}

__global__ void k_pool(const float* __restrict__ h2, const int* __restrict__ batch,
                       float* __restrict__ gsum, float* __restrict__ gcnt, int n) {
    int g = blockIdx.x / POOL_SLICES;
    int slice = blockIdx.x - g * POOL_SLICES;
    __shared__ int sbeg, send;
    if (threadIdx.x == 0) { sbeg = lowerb(batch, n, g); send = lowerb(batch, n, g + 1); }
    __syncthreads();
    int beg = sbeg, end = send;
    int f = threadIdx.x & 31;
    int r = threadIdx.x >> 5;   // 8 row-groups
    float acc = 0.f;
    for (int i = beg + slice * 8 + r; i < end; i += POOL_SLICES * 8)
        acc += h2[(size_t)i * 32 + f];
    __shared__ float red[256];
    red[threadIdx.x] = acc;
    __syncthreads();
    if (r == 0) {
        float s = 0.f;
#pragma unroll
        for (int q = 0; q < 8; ++q) s += red[q * 32 + f];
        atomicAdd(&gsum[g * 32 + f], s);
    }
    if (slice == 0 && threadIdx.x == 0) gcnt[g] = (float)(end - beg);
}

__global__ void k_cls(const float* __restrict__ gsum, const float* __restrict__ gcnt,
                      const float* __restrict__ Wc, const float* __restrict__ bc,
                      float* __restrict__ outp) {
    int t = threadIdx.x;
    if (t >= N_GRAPHS * 10) return;
    int g = t / 10, c = t - g * 10;
    float cv = fmaxf(gcnt[g], 1.f);
    float acc = bc[c];
#pragma unroll
    for (int k = 0; k < 32; ++k) acc += (gsum[g * 32 + k] / cv) * Wc[k * 10 + c];
    outp[g * 10 + c] = acc;
}

// ---------------- launch ----------------

extern "C" void kernel_launch(void* const* d_in, const int* in_sizes, int n_in,
                              void* d_out, int out_size, void* d_ws, size_t ws_size,
                              hipStream_t stream) {
    const float* x    = (const float*)d_in[0];
    const int*   ei   = (const int*)d_in[1];
    const int*   batch= (const int*)d_in[2];
    const float* W1l  = (const float*)d_in[3];
    const float* b1   = (const float*)d_in[4];
    const float* W1r  = (const float*)d_in[5];
    const float* W2l  = (const float*)d_in[6];
    const float* b2   = (const float*)d_in[7];
    const float* W2r  = (const float*)d_in[8];
    const float* W3l  = (const float*)d_in[9];
    const float* b3   = (const float*)d_in[10];
    const float* W3r  = (const float*)d_in[11];
    const float* Wc   = (const float*)d_in[12];
    const float* bc   = (const float*)d_in[13];
    float* out = (float*)d_out;

    char* ws = (char*)d_ws;
    size_t off = 0;
    auto alloc = [&](size_t bytes) { size_t o = off; off += (bytes + 255) & ~(size_t)255; return o; };

    int*    rs    = (int*)(ws + alloc((size_t)(N_NODES + 1) * 4));
    int*    perm  = (int*)(ws + alloc((size_t)(N_EDGES + 8) * 4));
    int*    gh    = (int*)(ws + alloc((size_t)NBUCK * NBLK * 4));
    int*    btotal= (int*)(ws + alloc(256 * 4));
    int*    bstart= (int*)(ws + alloc(260 * 4));
    unsigned long long* deltas = (unsigned long long*)(ws + alloc((size_t)N_NODES * 8));
    __half* y1    = (__half*)(ws + alloc((size_t)N_NODES * 16 * 2));
    float*  s1    = (float*)(ws + alloc((size_t)N_NODES * 16 * 4));
    __half* h     = (__half*)(ws + alloc((size_t)N_NODES * 16 * 2));
    float*  mean2 = (float*)(ws + alloc((size_t)N_NODES * 16 * 4));
    float*  h2    = (float*)(ws + alloc((size_t)N_NODES * 32 * 4));
    __half* y3    = (__half*)(ws + alloc((size_t)N_NODES * 24 * 2));
    float*  s3    = (float*)(ws + alloc((size_t)N_NODES * 21 * 4));
    float*  gsum  = (float*)(ws + alloc((size_t)N_GRAPHS * 32 * 4));
    float*  gcnt  = (float*)(ws + alloc((size_t)N_GRAPHS * 4));

    // tmp (12.8 MB) aliases h2 (12.8 MB): tmp dead before k_t2 writes h2
    unsigned* tmp = (unsigned*)h2;

    const int* src = ei;
    const int* dst = ei + N_EDGES;

    int nb = (N_NODES + 255) / 256;   // 391

    // CSR build (bucketed 2-pass counting sort, stripe-grouped adjacency)
    kp1_hist   <<<NBLK, 256, 0, stream>>>(dst, gh, N_EDGES);
    kp1_scanA  <<<NBUCK, 256, 0, stream>>>(gh, btotal);
    kp1_scanB  <<<1, 256, 0, stream>>>(btotal, bstart, rs, perm);
    kp1_scatter<<<NBLK, 256, 0, stream>>>(src, dst, gh, bstart, tmp, N_EDGES);
    kp2        <<<NBUCK, 1024, 0, stream>>>(tmp, bstart, rs, perm, deltas);

    // layer 1: transform-first (64->16), stripe-paced aggregate, +self, relu -> h (fp16)
    k_t1<<<nb, 256, 0, stream>>>(x, W1l, W1r, b1, y1, s1, N_NODES);
    k_agg<16, 16, true, true, true>
        <<<(N_NODES * 16 + 255) / 256, 256, 0, stream>>>(y1, rs, perm, deltas, s1, h, N_NODES);

    // layer 2: stripe-paced aggregate-first -> mean2 (f32), then 16->32
    k_agg<16, 16, false, false, false>
        <<<(N_NODES * 16 + 255) / 256, 256, 0, stream>>>(h, rs, perm, deltas, nullptr, mean2, N_NODES);
    k_t2<<<nb, 256, 0, stream>>>(mean2, h, W2l, W2r, b2, h2, N_NODES);

    // layer 3: transform-first on relu(h2) (32->21), stripe-paced aggregate, +self
    k_t3<<<nb, 256, 0, stream>>>(h2, W3l, W3r, b3, y3, s3, N_NODES);
    k_agg<21, 24, false, true, false>
        <<<(N_NODES * 21 + 255) / 256, 256, 0, stream>>>(y3, rs, perm, deltas, s3, out + N_GRAPHS * 10, N_NODES);

    // pooling over h2 (pre-relu, zero gsum first) + classifier
    hipMemsetAsync(gsum, 0, (size_t)N_GRAPHS * 32 * 4, stream);
    k_pool<<<N_GRAPHS * POOL_SLICES, 256, 0, stream>>>(h2, batch, gsum, gcnt, N_NODES);
    k_cls<<<1, 640, 0, stream>>>(gsum, gcnt, Wc, bc, out);
}

// Round 9
// 354.087 us; speedup vs baseline: 1.4868x; 1.2832x over previous
//
#include <hip/hip_runtime.h>
#include <hip/hip_fp16.h>
#include <cstdint>
#include <cstddef>

#define N_NODES  100000
#define N_EDGES  3200000
#define N_GRAPHS 64

#define BQBITS   9
#define BQ       512                      // nodes per bucket
#define NBUCK    196                      // ceil(100000/512)
#define TILE     4096                     // edges per pass-1 block
#define NBLK     782                      // ceil(3200000/4096)
#define POOL_SLICES 8

#define SPLIT    50000                    // src-half boundary
#define KEYS     1024                     // (node-local, half) keys per bucket

// ---------------- CSR build: bucketed 2-pass counting sort ----------------

__global__ void kp1_hist(const int* __restrict__ dst, int* __restrict__ gh, int ne) {
    __shared__ int h[NBUCK];
    for (int i = threadIdx.x; i < NBUCK; i += 256) h[i] = 0;
    __syncthreads();
    int base = blockIdx.x * TILE;
    for (int i = threadIdx.x; i < TILE; i += 256) {
        int e = base + i;
        if (e < ne) atomicAdd(&h[dst[e] >> BQBITS], 1);
    }
    __syncthreads();
    for (int i = threadIdx.x; i < NBUCK; i += 256) gh[i * NBLK + blockIdx.x] = h[i];
}

__global__ void kp1_scanA(int* __restrict__ gh, int* __restrict__ btotal) {
    int q = blockIdx.x;
    __shared__ int ts[256];
    int v[4];
    int tsum = 0;
#pragma unroll
    for (int u = 0; u < 4; ++u) {
        int idx = threadIdx.x * 4 + u;
        v[u] = (idx < NBLK) ? gh[q * NBLK + idx] : 0;
        tsum += v[u];
    }
    ts[threadIdx.x] = tsum;
    __syncthreads();
    for (int off = 1; off < 256; off <<= 1) {
        int t = (threadIdx.x >= off) ? ts[threadIdx.x - off] : 0;
        __syncthreads();
        ts[threadIdx.x] += t;
        __syncthreads();
    }
    int run = ts[threadIdx.x] - tsum;
#pragma unroll
    for (int u = 0; u < 4; ++u) {
        int idx = threadIdx.x * 4 + u;
        if (idx < NBLK) gh[q * NBLK + idx] = run;
        run += v[u];
    }
    if (threadIdx.x == 255) btotal[q] = ts[255];
}

__global__ void kp1_scanB(const int* __restrict__ btotal, int* __restrict__ bstart,
                          int* __restrict__ rs2, int* __restrict__ perm) {
    __shared__ int s[256];
    int v = (threadIdx.x < NBUCK) ? btotal[threadIdx.x] : 0;
    s[threadIdx.x] = v;
    __syncthreads();
    for (int off = 1; off < 256; off <<= 1) {
        int t = (threadIdx.x >= off) ? s[threadIdx.x - off] : 0;
        __syncthreads();
        s[threadIdx.x] += t;
        __syncthreads();
    }
    if (threadIdx.x < NBUCK) bstart[threadIdx.x] = s[threadIdx.x] - v;
    if (threadIdx.x == 0) { bstart[NBUCK] = N_EDGES; rs2[2 * N_NODES] = N_EDGES; }
    if (threadIdx.x < 8) perm[N_EDGES + threadIdx.x] = 0;   // pad
}

__global__ void kp1_scatter(const int* __restrict__ src, const int* __restrict__ dst,
                            const int* __restrict__ gh, const int* __restrict__ bstart,
                            unsigned* __restrict__ tmp, int ne) {
    __shared__ int lcnt[NBUCK];
    __shared__ int lbase[NBUCK];
    for (int i = threadIdx.x; i < NBUCK; i += 256) {
        lcnt[i] = 0;
        lbase[i] = bstart[i] + gh[i * NBLK + blockIdx.x];
    }
    __syncthreads();
    int base = blockIdx.x * TILE;
    for (int i = threadIdx.x; i < TILE; i += 256) {
        int e = base + i;
        if (e >= ne) continue;
        int d = dst[e], s = src[e];
        int q = d >> BQBITS;
        int r = atomicAdd(&lcnt[q], 1);
        tmp[lbase[q] + r] = ((unsigned)(d & (BQ - 1)) << 17) | (unsigned)s;
    }
}

// one block per bucket: (node-local, src-half) counting sort -> rs2 (2 segments/node), perm
__global__ void kp2(const unsigned* __restrict__ tmp, const int* __restrict__ bstart,
                    int* __restrict__ rs2, int* __restrict__ perm) {
    int q = blockIdx.x;
    int beg = bstart[q], end = bstart[q + 1];
    int m = end - beg;
    __shared__ int cnt[KEYS];
    __shared__ int lofs[KEYS];
    __shared__ int fill[KEYS];
    cnt[threadIdx.x] = 0; fill[threadIdx.x] = 0;
    __syncthreads();
    for (int p = threadIdx.x; p < m; p += 1024) {
        unsigned w = tmp[beg + p];
        int dl = w >> 17;
        int s = w & 0x1FFFF;
        atomicAdd(&cnt[dl * 2 + (s >= SPLIT)], 1);
    }
    __syncthreads();
    lofs[threadIdx.x] = cnt[threadIdx.x];
    __syncthreads();
    for (int off = 1; off < KEYS; off <<= 1) {
        int t = (threadIdx.x >= off) ? lofs[threadIdx.x - off] : 0;
        __syncthreads();
        lofs[threadIdx.x] += t;   // inclusive
        __syncthreads();
    }
    {
        int node = q * BQ + (threadIdx.x >> 1);
        if (node < N_NODES)
            rs2[q * KEYS + threadIdx.x] = beg + lofs[threadIdx.x] - cnt[threadIdx.x];
    }
    __syncthreads();
    for (int p = threadIdx.x; p < m; p += 1024) {
        unsigned w = tmp[beg + p];
        int dl = w >> 17;
        int s = w & 0x1FFFF;
        int key = dl * 2 + (s >= SPLIT);
        int r = atomicAdd(&fill[key], 1);
        perm[beg + lofs[key] - cnt[key] + r] = s;
    }
}

// ---------------- transforms ----------------

// y1(half) = x @ W1l ; s1(f32) = x @ W1r + b1      (64 -> 16)
__global__ void k_t1(const float* __restrict__ x, const float* __restrict__ W1l,
                     const float* __restrict__ W1r, const float* __restrict__ b1,
                     __half* __restrict__ y1, float* __restrict__ s1, int n) {
    __shared__ float wl[64 * 16], wr[64 * 16], bb[16];
    for (int i = threadIdx.x; i < 64 * 16; i += blockDim.x) { wl[i] = W1l[i]; wr[i] = W1r[i]; }
    if (threadIdx.x < 16) bb[threadIdx.x] = b1[threadIdx.x];
    __syncthreads();
    int node = blockIdx.x * blockDim.x + threadIdx.x;
    if (node >= n) return;
    const float4* xr = reinterpret_cast<const float4*>(x + (size_t)node * 64);
    float accl[16], accr[16];
#pragma unroll
    for (int j = 0; j < 16; ++j) { accl[j] = 0.f; accr[j] = 0.f; }
#pragma unroll
    for (int q = 0; q < 16; ++q) {
        float4 v = xr[q];
        float xs[4] = {v.x, v.y, v.z, v.w};
#pragma unroll
        for (int u = 0; u < 4; ++u) {
            int k = q * 4 + u;
            float xv = xs[u];
#pragma unroll
            for (int j = 0; j < 16; ++j) {
                accl[j] += xv * wl[k * 16 + j];
                accr[j] += xv * wr[k * 16 + j];
            }
        }
    }
    alignas(16) __half yh[16];
#pragma unroll
    for (int j = 0; j < 16; ++j) yh[j] = __float2half(accl[j]);
    uint4* y4 = reinterpret_cast<uint4*>(y1 + (size_t)node * 16);
    const uint4* yv = reinterpret_cast<const uint4*>(yh);
    y4[0] = yv[0]; y4[1] = yv[1];
    float4* s4 = reinterpret_cast<float4*>(s1 + (size_t)node * 16);
#pragma unroll
    for (int q = 0; q < 4; ++q)
        s4[q] = make_float4(accr[q*4+0] + bb[q*4+0], accr[q*4+1] + bb[q*4+1],
                            accr[q*4+2] + bb[q*4+2], accr[q*4+3] + bb[q*4+3]);
}

// h2(f32) = mean2 @ W2l + h(half) @ W2r + b2      (16 -> 32)
__global__ void k_t2(const float* __restrict__ mean2, const __half* __restrict__ h,
                     const float* __restrict__ W2l, const float* __restrict__ W2r,
                     const float* __restrict__ b2, float* __restrict__ h2, int n) {
    __shared__ float wl[16 * 32], wr[16 * 32], bb[32];
    for (int i = threadIdx.x; i < 16 * 32; i += blockDim.x) { wl[i] = W2l[i]; wr[i] = W2r[i]; }
    if (threadIdx.x < 32) bb[threadIdx.x] = b2[threadIdx.x];
    __syncthreads();
    int node = blockIdx.x * blockDim.x + threadIdx.x;
    if (node >= n) return;
    float m[16], hh[16];
    const float4* m4 = reinterpret_cast<const float4*>(mean2 + (size_t)node * 16);
#pragma unroll
    for (int q = 0; q < 4; ++q) {
        float4 a = m4[q];
        m[q*4+0]=a.x; m[q*4+1]=a.y; m[q*4+2]=a.z; m[q*4+3]=a.w;
    }
    alignas(16) __half hv[16];
    const uint4* hp = reinterpret_cast<const uint4*>(h + (size_t)node * 16);
    uint4* hvp = reinterpret_cast<uint4*>(hv);
    hvp[0] = hp[0]; hvp[1] = hp[1];
#pragma unroll
    for (int k = 0; k < 16; ++k) hh[k] = __half2float(hv[k]);
    float acc[32];
#pragma unroll
    for (int j = 0; j < 32; ++j) acc[j] = bb[j];
#pragma unroll
    for (int k = 0; k < 16; ++k) {
#pragma unroll
        for (int j = 0; j < 32; ++j)
            acc[j] += m[k] * wl[k * 32 + j] + hh[k] * wr[k * 32 + j];
    }
    float4* o4 = reinterpret_cast<float4*>(h2 + (size_t)node * 32);
#pragma unroll
    for (int q = 0; q < 8; ++q)
        o4[q] = make_float4(acc[q*4+0], acc[q*4+1], acc[q*4+2], acc[q*4+3]);
}

// z = relu(h2); y3(half, stride 24) = z @ W3l ; s3(f32) = z @ W3r + b3   (32 -> 21)
__global__ void k_t3(const float* __restrict__ h2, const float* __restrict__ W3l,
                     const float* __restrict__ W3r, const float* __restrict__ b3,
                     __half* __restrict__ y3, float* __restrict__ s3, int n) {
    __shared__ float wl[32 * 21], wr[32 * 21], bb[21];
    for (int i = threadIdx.x; i < 32 * 21; i += blockDim.x) { wl[i] = W3l[i]; wr[i] = W3r[i]; }
    if (threadIdx.x < 21) bb[threadIdx.x] = b3[threadIdx.x];
    __syncthreads();
    int node = blockIdx.x * blockDim.x + threadIdx.x;
    if (node >= n) return;
    float z[32];
    const float4* h4 = reinterpret_cast<const float4*>(h2 + (size_t)node * 32);
#pragma unroll
    for (int q = 0; q < 8; ++q) {
        float4 v = h4[q];
        z[q*4+0] = fmaxf(v.x, 0.f); z[q*4+1] = fmaxf(v.y, 0.f);
        z[q*4+2] = fmaxf(v.z, 0.f); z[q*4+3] = fmaxf(v.w, 0.f);
    }
    float a[21], c[21];
#pragma unroll
    for (int j = 0; j < 21; ++j) { a[j] = 0.f; c[j] = bb[j]; }
#pragma unroll
    for (int k = 0; k < 32; ++k) {
#pragma unroll
        for (int j = 0; j < 21; ++j) {
            a[j] += z[k] * wl[k * 21 + j];
            c[j] += z[k] * wr[k * 21 + j];
        }
    }
    alignas(16) __half yh[24];
#pragma unroll
    for (int j = 0; j < 21; ++j) yh[j] = __float2half(a[j]);
    yh[21] = __half(0.f); yh[22] = __half(0.f); yh[23] = __half(0.f);
    uint4* yp = reinterpret_cast<uint4*>(y3 + (size_t)node * 24);
    const uint4* yv = reinterpret_cast<const uint4*>(yh);
    yp[0] = yv[0]; yp[1] = yv[1]; yp[2] = yv[2];
    float* so = s3 + (size_t)node * 21;
#pragma unroll
    for (int j = 0; j < 21; ++j) so[j] = c[j];
}

// ---- aggregation: 2 launches per agg, split by src-half (window-paced) ----

template <int F, int STRIDE, int PASS, bool RELU, bool SELF, bool OUT_HALF>
__global__ void k_agg(const __half* __restrict__ y, const int* __restrict__ rs2,
                      const int* __restrict__ perm, float* __restrict__ accbuf,
                      const float* __restrict__ self,
                      void* __restrict__ outp, int n_nodes) {
    int t = blockIdx.x * blockDim.x + threadIdx.x;
    int node = t / F;
    int f = t - node * F;
    if (node >= n_nodes) return;
    int n2 = node * 2;
    int segb, sege, deg = 0;
    if constexpr (PASS == 0) {
        segb = rs2[n2]; sege = rs2[n2 + 1];
    } else {
        int a = rs2[n2]; segb = rs2[n2 + 1]; sege = rs2[n2 + 2];
        deg = sege - a;
    }
    float acc = 0.f;
    int e = segb;
    for (; e + 8 <= sege; e += 8) {
        int s0 = __builtin_nontemporal_load(&perm[e]);
        int s1 = __builtin_nontemporal_load(&perm[e + 1]);
        int s2 = __builtin_nontemporal_load(&perm[e + 2]);
        int s3 = __builtin_nontemporal_load(&perm[e + 3]);
        int s4 = __builtin_nontemporal_load(&perm[e + 4]);
        int s5 = __builtin_nontemporal_load(&perm[e + 5]);
        int s6 = __builtin_nontemporal_load(&perm[e + 6]);
        int s7 = __builtin_nontemporal_load(&perm[e + 7]);
        float v0 = __half2float(y[(size_t)s0 * STRIDE + f]);
        float v1 = __half2float(y[(size_t)s1 * STRIDE + f]);
        float v2 = __half2float(y[(size_t)s2 * STRIDE + f]);
        float v3 = __half2float(y[(size_t)s3 * STRIDE + f]);
        float v4 = __half2float(y[(size_t)s4 * STRIDE + f]);
        float v5 = __half2float(y[(size_t)s5 * STRIDE + f]);
        float v6 = __half2float(y[(size_t)s6 * STRIDE + f]);
        float v7 = __half2float(y[(size_t)s7 * STRIDE + f]);
        acc += ((v0 + v1) + (v2 + v3)) + ((v4 + v5) + (v6 + v7));
    }
    for (; e < sege; ++e) {
        int s = __builtin_nontemporal_load(&perm[e]);
        acc += __half2float(y[(size_t)s * STRIDE + f]);
    }
    if constexpr (PASS == 0) {
        __builtin_nontemporal_store(acc, &accbuf[(size_t)node * F + f]);
    } else {
        float v = acc + __builtin_nontemporal_load(&accbuf[(size_t)node * F + f]);
        v = v / fmaxf((float)deg, 1.0f);
        if (SELF) v += __builtin_nontemporal_load(&self[(size_t)node * F + f]);
        if (RELU) v = fmaxf(v, 0.f);
        if constexpr (OUT_HALF) {
            __half hv = __float2half(v);
            unsigned short bits = *reinterpret_cast<unsigned short*>(&hv);
            __builtin_nontemporal_store(bits, (unsigned short*)outp + (size_t)node * F + f);
        } else {
            __builtin_nontemporal_store(v, (float*)outp + (size_t)node * F + f);
        }
    }
}

// ---------------- pooling + classifier ----------------

__device__ __forceinline__ int lowerb(const int* a, int n, int key) {
    int lo = 0, hi = n;
    while (lo < hi) { int mid = (lo + hi) >> 1; if (a[mid] < key) lo = mid + 1; else hi = mid; }
    return lo;
}

__global__ void k_pool(const float* __restrict__ h2, const int* __restrict__ batch,
                       float* __restrict__ gsum, float* __restrict__ gcnt, int n) {
    int g = blockIdx.x / POOL_SLICES;
    int slice = blockIdx.x - g * POOL_SLICES;
    __shared__ int sbeg, send;
    if (threadIdx.x == 0) { sbeg = lowerb(batch, n, g); send = lowerb(batch, n, g + 1); }
    __syncthreads();
    int beg = sbeg, end = send;
    int f = threadIdx.x & 31;
    int r = threadIdx.x >> 5;   // 8 row-groups
    float acc = 0.f;
    for (int i = beg + slice * 8 + r; i < end; i += POOL_SLICES * 8)
        acc += h2[(size_t)i * 32 + f];
    __shared__ float red[256];
    red[threadIdx.x] = acc;
    __syncthreads();
    if (r == 0) {
        float s = 0.f;
#pragma unroll
        for (int q = 0; q < 8; ++q) s += red[q * 32 + f];
        atomicAdd(&gsum[g * 32 + f], s);
    }
    if (slice == 0 && threadIdx.x == 0) gcnt[g] = (float)(end - beg);
}

__global__ void k_cls(const float* __restrict__ gsum, const float* __restrict__ gcnt,
                      const float* __restrict__ Wc, const float* __restrict__ bc,
                      float* __restrict__ outp) {
    int t = threadIdx.x;
    if (t >= N_GRAPHS * 10) return;
    int g = t / 10, c = t - g * 10;
    float cv = fmaxf(gcnt[g], 1.f);
    float acc = bc[c];
#pragma unroll
    for (int k = 0; k < 32; ++k) acc += (gsum[g * 32 + k] / cv) * Wc[k * 10 + c];
    outp[g * 10 + c] = acc;
}

// ---------------- launch ----------------

extern "C" void kernel_launch(void* const* d_in, const int* in_sizes, int n_in,
                              void* d_out, int out_size, void* d_ws, size_t ws_size,
                              hipStream_t stream) {
    const float* x    = (const float*)d_in[0];
    const int*   ei   = (const int*)d_in[1];
    const int*   batch= (const int*)d_in[2];
    const float* W1l  = (const float*)d_in[3];
    const float* b1   = (const float*)d_in[4];
    const float* W1r  = (const float*)d_in[5];
    const float* W2l  = (const float*)d_in[6];
    const float* b2   = (const float*)d_in[7];
    const float* W2r  = (const float*)d_in[8];
    const float* W3l  = (const float*)d_in[9];
    const float* b3   = (const float*)d_in[10];
    const float* W3r  = (const float*)d_in[11];
    const float* Wc   = (const float*)d_in[12];
    const float* bc   = (const float*)d_in[13];
    float* out = (float*)d_out;

    char* ws = (char*)d_ws;
    size_t off = 0;
    auto alloc = [&](size_t bytes) { size_t o = off; off += (bytes + 255) & ~(size_t)255; return o; };

    int*    rs2   = (int*)(ws + alloc((size_t)(2 * N_NODES + 1) * 4));
    int*    perm  = (int*)(ws + alloc((size_t)(N_EDGES + 8) * 4));
    int*    gh    = (int*)(ws + alloc((size_t)NBUCK * NBLK * 4));
    int*    btotal= (int*)(ws + alloc(256 * 4));
    int*    bstart= (int*)(ws + alloc(260 * 4));
    float*  accbuf= (float*)(ws + alloc((size_t)N_NODES * 24 * 4));
    __half* y1    = (__half*)(ws + alloc((size_t)N_NODES * 16 * 2));
    float*  s1    = (float*)(ws + alloc((size_t)N_NODES * 16 * 4));
    __half* h     = (__half*)(ws + alloc((size_t)N_NODES * 16 * 2));
    float*  mean2 = (float*)(ws + alloc((size_t)N_NODES * 16 * 4));
    float*  h2    = (float*)(ws + alloc((size_t)N_NODES * 32 * 4));
    __half* y3    = (__half*)(ws + alloc((size_t)N_NODES * 24 * 2));
    float*  s3    = (float*)(ws + alloc((size_t)N_NODES * 21 * 4));
    float*  gsum  = (float*)(ws + alloc((size_t)N_GRAPHS * 32 * 4));
    float*  gcnt  = (float*)(ws + alloc((size_t)N_GRAPHS * 4));

    // tmp (12.8 MB) aliases h2 (12.8 MB): tmp dead before k_t2 writes h2
    unsigned* tmp = (unsigned*)h2;

    const int* src = ei;
    const int* dst = ei + N_EDGES;

    int nb  = (N_NODES + 255) / 256;                 // 391
    int g16 = (N_NODES * 16 + 255) / 256;            // 6250
    int g21 = (N_NODES * 21 + 255) / 256;            // 8204

    // CSR build (bucketed 2-pass counting sort, src-half-grouped adjacency)
    kp1_hist   <<<NBLK, 256, 0, stream>>>(dst, gh, N_EDGES);
    kp1_scanA  <<<NBUCK, 256, 0, stream>>>(gh, btotal);
    kp1_scanB  <<<1, 256, 0, stream>>>(btotal, bstart, rs2, perm);
    kp1_scatter<<<NBLK, 256, 0, stream>>>(src, dst, gh, bstart, tmp, N_EDGES);
    kp2        <<<NBUCK, 1024, 0, stream>>>(tmp, bstart, rs2, perm);

    // layer 1: transform-first (64->16); 2-pass windowed aggregate, +self, relu -> h
    k_t1<<<nb, 256, 0, stream>>>(x, W1l, W1r, b1, y1, s1, N_NODES);
    k_agg<16, 16, 0, false, false, false><<<g16, 256, 0, stream>>>(y1, rs2, perm, accbuf, nullptr, nullptr, N_NODES);
    k_agg<16, 16, 1, true,  true,  true ><<<g16, 256, 0, stream>>>(y1, rs2, perm, accbuf, s1, h, N_NODES);

    // layer 2: 2-pass windowed aggregate-first -> mean2 (f32), then 16->32
    k_agg<16, 16, 0, false, false, false><<<g16, 256, 0, stream>>>(h, rs2, perm, accbuf, nullptr, nullptr, N_NODES);
    k_agg<16, 16, 1, false, false, false><<<g16, 256, 0, stream>>>(h, rs2, perm, accbuf, nullptr, mean2, N_NODES);
    k_t2<<<nb, 256, 0, stream>>>(mean2, h, W2l, W2r, b2, h2, N_NODES);

    // layer 3: transform-first on relu(h2) (32->21); 2-pass windowed aggregate, +self
    k_t3<<<nb, 256, 0, stream>>>(h2, W3l, W3r, b3, y3, s3, N_NODES);
    k_agg<21, 24, 0, false, false, false><<<g21, 256, 0, stream>>>(y3, rs2, perm, accbuf, nullptr, nullptr, N_NODES);
    k_agg<21, 24, 1, false, true,  false><<<g21, 256, 0, stream>>>(y3, rs2, perm, accbuf, s3, out + N_GRAPHS * 10, N_NODES);

    // pooling over h2 (pre-relu, zero gsum first) + classifier
    hipMemsetAsync(gsum, 0, (size_t)N_GRAPHS * 32 * 4, stream);
    k_pool<<<N_GRAPHS * POOL_SLICES, 256, 0, stream>>>(h2, batch, gsum, gcnt, N_NODES);
    k_cls<<<1, 640, 0, stream>>>(gsum, gcnt, Wc, bc, out);
}

// Round 10
// 283.297 us; speedup vs baseline: 1.8583x; 1.2499x over previous
//
#include <hip/hip_runtime.h>
#include <hip/hip_fp16.h>
#include <cstdint>
#include <cstddef>

#define N_NODES  100000
#define N_EDGES  3200000
#define N_GRAPHS 64

#define BQBITS   9
#define BQ       512                      // nodes per bucket
#define NBUCK    196                      // ceil(100000/512)
#define TILE     4096                     // edges per pass-1 block
#define NBLK     782                      // ceil(3200000/4096)
#define POOL_SLICES 8

#define SPLIT    50000                    // src-half boundary (kept for kp2 layout)
#define KEYS     1024                     // (node-local, half) keys per bucket

// ---------------- CSR build: bucketed 2-pass counting sort ----------------

__global__ void kp1_hist(const int* __restrict__ dst, int* __restrict__ gh, int ne) {
    __shared__ int h[NBUCK];
    for (int i = threadIdx.x; i < NBUCK; i += 256) h[i] = 0;
    __syncthreads();
    int base = blockIdx.x * TILE;
    for (int i = threadIdx.x; i < TILE; i += 256) {
        int e = base + i;
        if (e < ne) atomicAdd(&h[dst[e] >> BQBITS], 1);
    }
    __syncthreads();
    for (int i = threadIdx.x; i < NBUCK; i += 256) gh[i * NBLK + blockIdx.x] = h[i];
}

__global__ void kp1_scanA(int* __restrict__ gh, int* __restrict__ btotal) {
    int q = blockIdx.x;
    __shared__ int ts[256];
    int v[4];
    int tsum = 0;
#pragma unroll
    for (int u = 0; u < 4; ++u) {
        int idx = threadIdx.x * 4 + u;
        v[u] = (idx < NBLK) ? gh[q * NBLK + idx] : 0;
        tsum += v[u];
    }
    ts[threadIdx.x] = tsum;
    __syncthreads();
    for (int off = 1; off < 256; off <<= 1) {
        int t = (threadIdx.x >= off) ? ts[threadIdx.x - off] : 0;
        __syncthreads();
        ts[threadIdx.x] += t;
        __syncthreads();
    }
    int run = ts[threadIdx.x] - tsum;
#pragma unroll
    for (int u = 0; u < 4; ++u) {
        int idx = threadIdx.x * 4 + u;
        if (idx < NBLK) gh[q * NBLK + idx] = run;
        run += v[u];
    }
    if (threadIdx.x == 255) btotal[q] = ts[255];
}

__global__ void kp1_scanB(const int* __restrict__ btotal, int* __restrict__ bstart,
                          int* __restrict__ rs2, int* __restrict__ perm) {
    __shared__ int s[256];
    int v = (threadIdx.x < NBUCK) ? btotal[threadIdx.x] : 0;
    s[threadIdx.x] = v;
    __syncthreads();
    for (int off = 1; off < 256; off <<= 1) {
        int t = (threadIdx.x >= off) ? s[threadIdx.x - off] : 0;
        __syncthreads();
        s[threadIdx.x] += t;
        __syncthreads();
    }
    if (threadIdx.x < NBUCK) bstart[threadIdx.x] = s[threadIdx.x] - v;
    if (threadIdx.x == 0) { bstart[NBUCK] = N_EDGES; rs2[2 * N_NODES] = N_EDGES; }
    if (threadIdx.x < 8) perm[N_EDGES + threadIdx.x] = 0;   // pad
}

// block-local counting sort -> bucket-runs in LDS -> coalesced run copy to tmp
__global__ __launch_bounds__(256) void kp1_scatter(
        const int* __restrict__ src, const int* __restrict__ dst,
        const int* __restrict__ gh, const int* __restrict__ bstart,
        unsigned* __restrict__ tmp, int ne) {
    __shared__ unsigned sed[TILE];        // 16 KB
    __shared__ int lcnt[NBUCK];
    __shared__ int lofs[NBUCK + 1];
    __shared__ int fill[NBUCK];
    __shared__ int delta[NBUCK];
    __shared__ int ts[256];
    for (int i = threadIdx.x; i < NBUCK; i += 256) { lcnt[i] = 0; fill[i] = 0; }
    __syncthreads();
    int base = blockIdx.x * TILE;
    int nh = ne - base; if (nh > TILE) nh = TILE;
    int myq[16]; unsigned myw[16];
#pragma unroll
    for (int u = 0; u < 16; ++u) {
        int i = u * 256 + threadIdx.x;
        myq[u] = -1;
        if (i < nh) {
            int d = dst[base + i], s = src[base + i];
            int q = d >> BQBITS;
            myq[u] = q;
            myw[u] = ((unsigned)(d & (BQ - 1)) << 17) | (unsigned)s;
            atomicAdd(&lcnt[q], 1);
        }
    }
    __syncthreads();
    int v = (threadIdx.x < NBUCK) ? lcnt[threadIdx.x] : 0;
    ts[threadIdx.x] = v;
    __syncthreads();
    for (int off = 1; off < 256; off <<= 1) {
        int t = (threadIdx.x >= off) ? ts[threadIdx.x - off] : 0;
        __syncthreads();
        ts[threadIdx.x] += t;
        __syncthreads();
    }
    if (threadIdx.x < NBUCK) {
        int start = ts[threadIdx.x] - v;
        lofs[threadIdx.x] = start;
        delta[threadIdx.x] = bstart[threadIdx.x] + gh[threadIdx.x * NBLK + blockIdx.x] - start;
    }
    if (threadIdx.x == NBUCK - 1) lofs[NBUCK] = ts[threadIdx.x];
    __syncthreads();
#pragma unroll
    for (int u = 0; u < 16; ++u) {
        if (myq[u] >= 0) {
            int r = atomicAdd(&fill[myq[u]], 1);
            sed[lofs[myq[u]] + r] = myw[u];
        }
    }
    __syncthreads();
    for (int p = threadIdx.x; p < nh; p += 256) {
        int lo = 0, hi = NBUCK;                 // run q = largest with lofs[q] <= p
        while (hi - lo > 1) { int mid = (lo + hi) >> 1; if (lofs[mid] <= p) lo = mid; else hi = mid; }
        tmp[p + delta[lo]] = sed[p];
    }
}

// one block per bucket: (node-local, src-half) counting sort -> rs2, perm
__global__ void kp2(const unsigned* __restrict__ tmp, const int* __restrict__ bstart,
                    int* __restrict__ rs2, int* __restrict__ perm) {
    int q = blockIdx.x;
    int beg = bstart[q], end = bstart[q + 1];
    int m = end - beg;
    __shared__ int cnt[KEYS];
    __shared__ int lofs[KEYS];
    __shared__ int fill[KEYS];
    cnt[threadIdx.x] = 0; fill[threadIdx.x] = 0;
    __syncthreads();
    for (int p = threadIdx.x; p < m; p += 1024) {
        unsigned w = tmp[beg + p];
        int dl = w >> 17;
        int s = w & 0x1FFFF;
        atomicAdd(&cnt[dl * 2 + (s >= SPLIT)], 1);
    }
    __syncthreads();
    lofs[threadIdx.x] = cnt[threadIdx.x];
    __syncthreads();
    for (int off = 1; off < KEYS; off <<= 1) {
        int t = (threadIdx.x >= off) ? lofs[threadIdx.x - off] : 0;
        __syncthreads();
        lofs[threadIdx.x] += t;   // inclusive
        __syncthreads();
    }
    {
        int node = q * BQ + (threadIdx.x >> 1);
        if (node < N_NODES)
            rs2[q * KEYS + threadIdx.x] = beg + lofs[threadIdx.x] - cnt[threadIdx.x];
    }
    __syncthreads();
    for (int p = threadIdx.x; p < m; p += 1024) {
        unsigned w = tmp[beg + p];
        int dl = w >> 17;
        int s = w & 0x1FFFF;
        int key = dl * 2 + (s >= SPLIT);
        int r = atomicAdd(&fill[key], 1);
        perm[beg + lofs[key] - cnt[key] + r] = s;
    }
}

// ---------------- transforms ----------------

// y1(half) = x @ W1l ; s1(f32) = x @ W1r + b1      (64 -> 16)
__global__ void k_t1(const float* __restrict__ x, const float* __restrict__ W1l,
                     const float* __restrict__ W1r, const float* __restrict__ b1,
                     __half* __restrict__ y1, float* __restrict__ s1, int n) {
    __shared__ float wl[64 * 16], wr[64 * 16], bb[16];
    for (int i = threadIdx.x; i < 64 * 16; i += blockDim.x) { wl[i] = W1l[i]; wr[i] = W1r[i]; }
    if (threadIdx.x < 16) bb[threadIdx.x] = b1[threadIdx.x];
    __syncthreads();
    int node = blockIdx.x * blockDim.x + threadIdx.x;
    if (node >= n) return;
    const float4* xr = reinterpret_cast<const float4*>(x + (size_t)node * 64);
    float accl[16], accr[16];
#pragma unroll
    for (int j = 0; j < 16; ++j) { accl[j] = 0.f; accr[j] = 0.f; }
#pragma unroll
    for (int q = 0; q < 16; ++q) {
        float4 v = xr[q];
        float xs[4] = {v.x, v.y, v.z, v.w};
#pragma unroll
        for (int u = 0; u < 4; ++u) {
            int k = q * 4 + u;
            float xv = xs[u];
#pragma unroll
            for (int j = 0; j < 16; ++j) {
                accl[j] += xv * wl[k * 16 + j];
                accr[j] += xv * wr[k * 16 + j];
            }
        }
    }
    alignas(16) __half yh[16];
#pragma unroll
    for (int j = 0; j < 16; ++j) yh[j] = __float2half(accl[j]);
    uint4* y4 = reinterpret_cast<uint4*>(y1 + (size_t)node * 16);
    const uint4* yv = reinterpret_cast<const uint4*>(yh);
    y4[0] = yv[0]; y4[1] = yv[1];
    float4* s4 = reinterpret_cast<float4*>(s1 + (size_t)node * 16);
#pragma unroll
    for (int q = 0; q < 4; ++q)
        s4[q] = make_float4(accr[q*4+0] + bb[q*4+0], accr[q*4+1] + bb[q*4+1],
                            accr[q*4+2] + bb[q*4+2], accr[q*4+3] + bb[q*4+3]);
}

// h2(f32) = mean2 @ W2l + h(half) @ W2r + b2      (16 -> 32)
__global__ void k_t2(const float* __restrict__ mean2, const __half* __restrict__ h,
                     const float* __restrict__ W2l, const float* __restrict__ W2r,
                     const float* __restrict__ b2, float* __restrict__ h2, int n) {
    __shared__ float wl[16 * 32], wr[16 * 32], bb[32];
    for (int i = threadIdx.x; i < 16 * 32; i += blockDim.x) { wl[i] = W2l[i]; wr[i] = W2r[i]; }
    if (threadIdx.x < 32) bb[threadIdx.x] = b2[threadIdx.x];
    __syncthreads();
    int node = blockIdx.x * blockDim.x + threadIdx.x;
    if (node >= n) return;
    float m[16], hh[16];
    const float4* m4 = reinterpret_cast<const float4*>(mean2 + (size_t)node * 16);
#pragma unroll
    for (int q = 0; q < 4; ++q) {
        float4 a = m4[q];
        m[q*4+0]=a.x; m[q*4+1]=a.y; m[q*4+2]=a.z; m[q*4+3]=a.w;
    }
    alignas(16) __half hv[16];
    const uint4* hp = reinterpret_cast<const uint4*>(h + (size_t)node * 16);
    uint4* hvp = reinterpret_cast<uint4*>(hv);
    hvp[0] = hp[0]; hvp[1] = hp[1];
#pragma unroll
    for (int k = 0; k < 16; ++k) hh[k] = __half2float(hv[k]);
    float acc[32];
#pragma unroll
    for (int j = 0; j < 32; ++j) acc[j] = bb[j];
#pragma unroll
    for (int k = 0; k < 16; ++k) {
#pragma unroll
        for (int j = 0; j < 32; ++j)
            acc[j] += m[k] * wl[k * 32 + j] + hh[k] * wr[k * 32 + j];
    }
    float4* o4 = reinterpret_cast<float4*>(h2 + (size_t)node * 32);
#pragma unroll
    for (int q = 0; q < 8; ++q)
        o4[q] = make_float4(acc[q*4+0], acc[q*4+1], acc[q*4+2], acc[q*4+3]);
}

// z = relu(h2); y3(half, stride 24) = z @ W3l ; s3(f32) = z @ W3r + b3   (32 -> 21)
__global__ void k_t3(const float* __restrict__ h2, const float* __restrict__ W3l,
                     const float* __restrict__ W3r, const float* __restrict__ b3,
                     __half* __restrict__ y3, float* __restrict__ s3, int n) {
    __shared__ float wl[32 * 21], wr[32 * 21], bb[21];
    for (int i = threadIdx.x; i < 32 * 21; i += blockDim.x) { wl[i] = W3l[i]; wr[i] = W3r[i]; }
    if (threadIdx.x < 21) bb[threadIdx.x] = b3[threadIdx.x];
    __syncthreads();
    int node = blockIdx.x * blockDim.x + threadIdx.x;
    if (node >= n) return;
    float z[32];
    const float4* h4 = reinterpret_cast<const float4*>(h2 + (size_t)node * 32);
#pragma unroll
    for (int q = 0; q < 8; ++q) {
        float4 v = h4[q];
        z[q*4+0] = fmaxf(v.x, 0.f); z[q*4+1] = fmaxf(v.y, 0.f);
        z[q*4+2] = fmaxf(v.z, 0.f); z[q*4+3] = fmaxf(v.w, 0.f);
    }
    float a[21], c[21];
#pragma unroll
    for (int j = 0; j < 21; ++j) { a[j] = 0.f; c[j] = bb[j]; }
#pragma unroll
    for (int k = 0; k < 32; ++k) {
#pragma unroll
        for (int j = 0; j < 21; ++j) {
            a[j] += z[k] * wl[k * 21 + j];
            c[j] += z[k] * wr[k * 21 + j];
        }
    }
    alignas(16) __half yh[24];
#pragma unroll
    for (int j = 0; j < 21; ++j) yh[j] = __float2half(a[j]);
    yh[21] = __half(0.f); yh[22] = __half(0.f); yh[23] = __half(0.f);
    uint4* yp = reinterpret_cast<uint4*>(y3 + (size_t)node * 24);
    const uint4* yv = reinterpret_cast<const uint4*>(yh);
    yp[0] = yv[0]; yp[1] = yv[1]; yp[2] = yv[2];
    float* so = s3 + (size_t)node * 21;
#pragma unroll
    for (int j = 0; j < 21; ++j) so[j] = c[j];
}

// ---- aggregation (single pass over [rs2[2n], rs2[2n+2]), fp16 table) ----

// layers 1-2: 8 threads/node, half2 per thread
template <bool RELU, bool SELF, bool OUT_HALF>
__global__ void k_agg8(const __half2* __restrict__ y2, const int* __restrict__ rs2,
                       const int* __restrict__ perm, const float* __restrict__ self,
                       void* __restrict__ outp, int n_nodes) {
    int t = blockIdx.x * blockDim.x + threadIdx.x;
    int node = t >> 3;
    int f = t & 7;
    if (node >= n_nodes) return;
    int beg = rs2[2 * node], end = rs2[2 * node + 2];
    float ax = 0.f, ay = 0.f;
    int e = beg;
    for (; e + 8 <= end; e += 8) {
        int s0 = __builtin_nontemporal_load(&perm[e]);
        int s1 = __builtin_nontemporal_load(&perm[e + 1]);
        int s2 = __builtin_nontemporal_load(&perm[e + 2]);
        int s3 = __builtin_nontemporal_load(&perm[e + 3]);
        int s4 = __builtin_nontemporal_load(&perm[e + 4]);
        int s5 = __builtin_nontemporal_load(&perm[e + 5]);
        int s6 = __builtin_nontemporal_load(&perm[e + 6]);
        int s7 = __builtin_nontemporal_load(&perm[e + 7]);
        __half2 v0 = y2[(size_t)s0 * 8 + f];
        __half2 v1 = y2[(size_t)s1 * 8 + f];
        __half2 v2 = y2[(size_t)s2 * 8 + f];
        __half2 v3 = y2[(size_t)s3 * 8 + f];
        __half2 v4 = y2[(size_t)s4 * 8 + f];
        __half2 v5 = y2[(size_t)s5 * 8 + f];
        __half2 v6 = y2[(size_t)s6 * 8 + f];
        __half2 v7 = y2[(size_t)s7 * 8 + f];
        ax += ((__low2float(v0) + __low2float(v1)) + (__low2float(v2) + __low2float(v3)))
            + ((__low2float(v4) + __low2float(v5)) + (__low2float(v6) + __low2float(v7)));
        ay += ((__high2float(v0) + __high2float(v1)) + (__high2float(v2) + __high2float(v3)))
            + ((__high2float(v4) + __high2float(v5)) + (__high2float(v6) + __high2float(v7)));
    }
    for (; e < end; ++e) {
        int s = __builtin_nontemporal_load(&perm[e]);
        __half2 v = y2[(size_t)s * 8 + f];
        ax += __low2float(v);
        ay += __high2float(v);
    }
    float inv = 1.0f / fmaxf((float)(end - beg), 1.0f);
    ax *= inv; ay *= inv;
    if (SELF) {
        const float* sp = self + (size_t)node * 16 + 2 * f;
        ax += __builtin_nontemporal_load(sp);
        ay += __builtin_nontemporal_load(sp + 1);
    }
    if (RELU) { ax = fmaxf(ax, 0.f); ay = fmaxf(ay, 0.f); }
    if constexpr (OUT_HALF) {
        __half2 hv = __floats2half2_rn(ax, ay);
        unsigned u = *reinterpret_cast<unsigned*>(&hv);
        __builtin_nontemporal_store(u, (unsigned*)outp + (size_t)node * 8 + f);
    } else {
        float* op = (float*)outp + (size_t)node * 16 + 2 * f;
        __builtin_nontemporal_store(ax, op);
        __builtin_nontemporal_store(ay, op + 1);
    }
}

// layer 3: scalar, F=21 threads/node, stride-24 table
__global__ void k_agg21(const __half* __restrict__ y, const int* __restrict__ rs2,
                        const int* __restrict__ perm, const float* __restrict__ self,
                        float* __restrict__ outp, int n_nodes) {
    int t = blockIdx.x * blockDim.x + threadIdx.x;
    int node = t / 21;
    int f = t - node * 21;
    if (node >= n_nodes) return;
    int beg = rs2[2 * node], end = rs2[2 * node + 2];
    float acc = 0.f;
    int e = beg;
    for (; e + 8 <= end; e += 8) {
        int s0 = __builtin_nontemporal_load(&perm[e]);
        int s1 = __builtin_nontemporal_load(&perm[e + 1]);
        int s2 = __builtin_nontemporal_load(&perm[e + 2]);
        int s3 = __builtin_nontemporal_load(&perm[e + 3]);
        int s4 = __builtin_nontemporal_load(&perm[e + 4]);
        int s5 = __builtin_nontemporal_load(&perm[e + 5]);
        int s6 = __builtin_nontemporal_load(&perm[e + 6]);
        int s7 = __builtin_nontemporal_load(&perm[e + 7]);
        float v0 = __half2float(y[(size_t)s0 * 24 + f]);
        float v1 = __half2float(y[(size_t)s1 * 24 + f]);
        float v2 = __half2float(y[(size_t)s2 * 24 + f]);
        float v3 = __half2float(y[(size_t)s3 * 24 + f]);
        float v4 = __half2float(y[(size_t)s4 * 24 + f]);
        float v5 = __half2float(y[(size_t)s5 * 24 + f]);
        float v6 = __half2float(y[(size_t)s6 * 24 + f]);
        float v7 = __half2float(y[(size_t)s7 * 24 + f]);
        acc += ((v0 + v1) + (v2 + v3)) + ((v4 + v5) + (v6 + v7));
    }
    for (; e < end; ++e) {
        int s = __builtin_nontemporal_load(&perm[e]);
        acc += __half2float(y[(size_t)s * 24 + f]);
    }
    float v = acc / fmaxf((float)(end - beg), 1.0f);
    v += __builtin_nontemporal_load(&self[(size_t)node * 21 + f]);
    __builtin_nontemporal_store(v, &outp[(size_t)node * 21 + f]);
}

// ---------------- pooling + classifier ----------------

__device__ __forceinline__ int lowerb(const int* a, int n, int key) {
    int lo = 0, hi = n;
    while (lo < hi) { int mid = (lo + hi) >> 1; if (a[mid] < key) lo = mid + 1; else hi = mid; }
    return lo;
}

__global__ void k_pool(const float* __restrict__ h2, const int* __restrict__ batch,
                       float* __restrict__ gsum, float* __restrict__ gcnt, int n) {
    int g = blockIdx.x / POOL_SLICES;
    int slice = blockIdx.x - g * POOL_SLICES;
    __shared__ int sbeg, send;
    if (threadIdx.x == 0) { sbeg = lowerb(batch, n, g); send = lowerb(batch, n, g + 1); }
    __syncthreads();
    int beg = sbeg, end = send;
    int f = threadIdx.x & 31;
    int r = threadIdx.x >> 5;   // 8 row-groups
    float acc = 0.f;
    for (int i = beg + slice * 8 + r; i < end; i += POOL_SLICES * 8)
        acc += h2[(size_t)i * 32 + f];
    __shared__ float red[256];
    red[threadIdx.x] = acc;
    __syncthreads();
    if (r == 0) {
        float s = 0.f;
#pragma unroll
        for (int q = 0; q < 8; ++q) s += red[q * 32 + f];
        atomicAdd(&gsum[g * 32 + f], s);
    }
    if (slice == 0 && threadIdx.x == 0) gcnt[g] = (float)(end - beg);
}

__global__ void k_cls(const float* __restrict__ gsum, const float* __restrict__ gcnt,
                      const float* __restrict__ Wc, const float* __restrict__ bc,
                      float* __restrict__ outp) {
    int t = threadIdx.x;
    if (t >= N_GRAPHS * 10) return;
    int g = t / 10, c = t - g * 10;
    float cv = fmaxf(gcnt[g], 1.f);
    float acc = bc[c];
#pragma unroll
    for (int k = 0; k < 32; ++k) acc += (gsum[g * 32 + k] / cv) * Wc[k * 10 + c];
    outp[g * 10 + c] = acc;
}

// ---------------- launch ----------------

extern "C" void kernel_launch(void* const* d_in, const int* in_sizes, int n_in,
                              void* d_out, int out_size, void* d_ws, size_t ws_size,
                              hipStream_t stream) {
    const float* x    = (const float*)d_in[0];
    const int*   ei   = (const int*)d_in[1];
    const int*   batch= (const int*)d_in[2];
    const float* W1l  = (const float*)d_in[3];
    const float* b1   = (const float*)d_in[4];
    const float* W1r  = (const float*)d_in[5];
    const float* W2l  = (const float*)d_in[6];
    const float* b2   = (const float*)d_in[7];
    const float* W2r  = (const float*)d_in[8];
    const float* W3l  = (const float*)d_in[9];
    const float* b3   = (const float*)d_in[10];
    const float* W3r  = (const float*)d_in[11];
    const float* Wc   = (const float*)d_in[12];
    const float* bc   = (const float*)d_in[13];
    float* out = (float*)d_out;

    char* ws = (char*)d_ws;
    size_t off = 0;
    auto alloc = [&](size_t bytes) { size_t o = off; off += (bytes + 255) & ~(size_t)255; return o; };

    int*    rs2   = (int*)(ws + alloc((size_t)(2 * N_NODES + 1) * 4));
    int*    perm  = (int*)(ws + alloc((size_t)(N_EDGES + 8) * 4));
    int*    gh    = (int*)(ws + alloc((size_t)NBUCK * NBLK * 4));
    int*    btotal= (int*)(ws + alloc(256 * 4));
    int*    bstart= (int*)(ws + alloc(260 * 4));
    __half* y1    = (__half*)(ws + alloc((size_t)N_NODES * 16 * 2));
    float*  s1    = (float*)(ws + alloc((size_t)N_NODES * 16 * 4));
    __half* h     = (__half*)(ws + alloc((size_t)N_NODES * 16 * 2));
    float*  mean2 = (float*)(ws + alloc((size_t)N_NODES * 16 * 4));
    float*  h2    = (float*)(ws + alloc((size_t)N_NODES * 32 * 4));
    __half* y3    = (__half*)(ws + alloc((size_t)N_NODES * 24 * 2));
    float*  s3    = (float*)(ws + alloc((size_t)N_NODES * 21 * 4));
    float*  gsum  = (float*)(ws + alloc((size_t)N_GRAPHS * 32 * 4));
    float*  gcnt  = (float*)(ws + alloc((size_t)N_GRAPHS * 4));

    // tmp (12.8 MB) aliases h2 (12.8 MB): tmp dead before k_t2 writes h2
    unsigned* tmp = (unsigned*)h2;

    const int* src = ei;
    const int* dst = ei + N_EDGES;

    int nb  = (N_NODES + 255) / 256;                 // 391
    int g8  = (N_NODES * 8 + 255) / 256;             // 3125
    int g21 = (N_NODES * 21 + 255) / 256;            // 8204

    // CSR build
    kp1_hist   <<<NBLK, 256, 0, stream>>>(dst, gh, N_EDGES);
    kp1_scanA  <<<NBUCK, 256, 0, stream>>>(gh, btotal);
    kp1_scanB  <<<1, 256, 0, stream>>>(btotal, bstart, rs2, perm);
    kp1_scatter<<<NBLK, 256, 0, stream>>>(src, dst, gh, bstart, tmp, N_EDGES);
    kp2        <<<NBUCK, 1024, 0, stream>>>(tmp, bstart, rs2, perm);

    // layer 1: transform-first (64->16); single-pass aggregate (+self +relu) -> h (fp16)
    k_t1<<<nb, 256, 0, stream>>>(x, W1l, W1r, b1, y1, s1, N_NODES);
    k_agg8<true, true, true><<<g8, 256, 0, stream>>>(
        (const __half2*)y1, rs2, perm, s1, h, N_NODES);

    // layer 2: aggregate-first -> mean2 (f32), then 16->32
    k_agg8<false, false, false><<<g8, 256, 0, stream>>>(
        (const __half2*)h, rs2, perm, nullptr, mean2, N_NODES);
    k_t2<<<nb, 256, 0, stream>>>(mean2, h, W2l, W2r, b2, h2, N_NODES);

    // layer 3: transform-first on relu(h2) (32->21); aggregate, +self
    k_t3<<<nb, 256, 0, stream>>>(h2, W3l, W3r, b3, y3, s3, N_NODES);
    k_agg21<<<g21, 256, 0, stream>>>(y3, rs2, perm, s3, out + N_GRAPHS * 10, N_NODES);

    // pooling over h2 (pre-relu, zero gsum first) + classifier
    hipMemsetAsync(gsum, 0, (size_t)N_GRAPHS * 32 * 4, stream);
    k_pool<<<N_GRAPHS * POOL_SLICES, 256, 0, stream>>>(h2, batch, gsum, gcnt, N_NODES);
    k_cls<<<1, 640, 0, stream>>>(gsum, gcnt, Wc, bc, out);
}

// Round 12
// 237.229 us; speedup vs baseline: 2.2192x; 1.1942x over previous
//
#include <hip/hip_runtime.h>
#include <hip/hip_fp16.h>
#include <cstdint>
#include <cstddef>

#define N_NODES  100000
#define N_EDGES  3200000
#define N_GRAPHS 64

#define BQBITS   9
#define BQ       512                      // nodes per bucket
#define NBUCK    196                      // ceil(100000/512)
#define TILE     4096                     // edges per pass-1 block
#define NBLK     782                      // ceil(3200000/4096)
#define POOL_SLICES 8
#define PADB     4608                     // per-bucket padding slack (512*7+8 rounded up)

// ---------------- CSR build: bucketed 2-pass counting sort ----------------

__global__ void kp1_hist(const int* __restrict__ dst, int* __restrict__ gh, int ne) {
    __shared__ int h[NBUCK];
    for (int i = threadIdx.x; i < NBUCK; i += 256) h[i] = 0;
    __syncthreads();
    int base = blockIdx.x * TILE;
    for (int i = threadIdx.x; i < TILE; i += 256) {
        int e = base + i;
        if (e < ne) atomicAdd(&h[dst[e] >> BQBITS], 1);
    }
    __syncthreads();
    for (int i = threadIdx.x; i < NBUCK; i += 256) gh[i * NBLK + blockIdx.x] = h[i];
}

__global__ void kp1_scanA(int* __restrict__ gh, int* __restrict__ btotal) {
    int q = blockIdx.x;
    __shared__ int ts[256];
    int v[4];
    int tsum = 0;
#pragma unroll
    for (int u = 0; u < 4; ++u) {
        int idx = threadIdx.x * 4 + u;
        v[u] = (idx < NBLK) ? gh[q * NBLK + idx] : 0;
        tsum += v[u];
    }
    ts[threadIdx.x] = tsum;
    __syncthreads();
    for (int off = 1; off < 256; off <<= 1) {
        int t = (threadIdx.x >= off) ? ts[threadIdx.x - off] : 0;
        __syncthreads();
        ts[threadIdx.x] += t;
        __syncthreads();
    }
    int run = ts[threadIdx.x] - tsum;
#pragma unroll
    for (int u = 0; u < 4; ++u) {
        int idx = threadIdx.x * 4 + u;
        if (idx < NBLK) gh[q * NBLK + idx] = run;
        run += v[u];
    }
    if (threadIdx.x == 255) btotal[q] = ts[255];
}

__global__ void kp1_scanB(const int* __restrict__ btotal, int* __restrict__ bstart) {
    __shared__ int s[256];
    int v = (threadIdx.x < NBUCK) ? btotal[threadIdx.x] : 0;
    s[threadIdx.x] = v;
    __syncthreads();
    for (int off = 1; off < 256; off <<= 1) {
        int t = (threadIdx.x >= off) ? s[threadIdx.x - off] : 0;
        __syncthreads();
        s[threadIdx.x] += t;
        __syncthreads();
    }
    if (threadIdx.x < NBUCK) bstart[threadIdx.x] = s[threadIdx.x] - v;
    if (threadIdx.x == 0) bstart[NBUCK] = N_EDGES;
}

// block-local counting sort -> bucket-runs in LDS -> coalesced run copy to tmp
__global__ __launch_bounds__(256) void kp1_scatter(
        const int* __restrict__ src, const int* __restrict__ dst,
        const int* __restrict__ gh, const int* __restrict__ bstart,
        unsigned* __restrict__ tmp, int ne) {
    __shared__ unsigned sed[TILE];        // 16 KB
    __shared__ int lcnt[NBUCK];
    __shared__ int lofs[NBUCK + 1];
    __shared__ int fill[NBUCK];
    __shared__ int delta[NBUCK];
    __shared__ int ts[256];
    for (int i = threadIdx.x; i < NBUCK; i += 256) { lcnt[i] = 0; fill[i] = 0; }
    __syncthreads();
    int base = blockIdx.x * TILE;
    int nh = ne - base; if (nh > TILE) nh = TILE;
    int myq[16]; unsigned myw[16];
#pragma unroll
    for (int u = 0; u < 16; ++u) {
        int i = u * 256 + threadIdx.x;
        myq[u] = -1;
        if (i < nh) {
            int d = dst[base + i], s = src[base + i];
            int q = d >> BQBITS;
            myq[u] = q;
            myw[u] = ((unsigned)(d & (BQ - 1)) << 17) | (unsigned)s;
            atomicAdd(&lcnt[q], 1);
        }
    }
    __syncthreads();
    int v = (threadIdx.x < NBUCK) ? lcnt[threadIdx.x] : 0;
    ts[threadIdx.x] = v;
    __syncthreads();
    for (int off = 1; off < 256; off <<= 1) {
        int t = (threadIdx.x >= off) ? ts[threadIdx.x - off] : 0;
        __syncthreads();
        ts[threadIdx.x] += t;
        __syncthreads();
    }
    if (threadIdx.x < NBUCK) {
        int start = ts[threadIdx.x] - v;
        lofs[threadIdx.x] = start;
        delta[threadIdx.x] = bstart[threadIdx.x] + gh[threadIdx.x * NBLK + blockIdx.x] - start;
    }
    if (threadIdx.x == NBUCK - 1) lofs[NBUCK] = ts[threadIdx.x];
    __syncthreads();
#pragma unroll
    for (int u = 0; u < 16; ++u) {
        if (myq[u] >= 0) {
            int r = atomicAdd(&fill[myq[u]], 1);
            sed[lofs[myq[u]] + r] = myw[u];
        }
    }
    __syncthreads();
    for (int p = threadIdx.x; p < nh; p += 256) {
        int lo = 0, hi = NBUCK;                 // run q = largest with lofs[q] <= p
        while (hi - lo > 1) { int mid = (lo + hi) >> 1; if (lofs[mid] <= p) lo = mid; else hi = mid; }
        tmp[p + delta[lo]] = sed[p];
    }
}

// one block per bucket: node counting sort -> rs/deg + 8-padded perm segments
__global__ void kp2(const unsigned* __restrict__ tmp, const int* __restrict__ bstart,
                    int* __restrict__ rs, int* __restrict__ deg, int* __restrict__ perm) {
    int q = blockIdx.x;
    int beg = bstart[q], end = bstart[q + 1];
    int m = end - beg;
    int pbase = ((beg + 7) & ~7) + q * PADB;
    __shared__ int cnt[BQ];
    __shared__ int lofs[BQ];
    __shared__ int fill[BQ];
    if (threadIdx.x < BQ) { cnt[threadIdx.x] = 0; fill[threadIdx.x] = 0; }
    __syncthreads();
    for (int p = threadIdx.x; p < m; p += 1024)
        atomicAdd(&cnt[tmp[beg + p] >> 17], 1);
    __syncthreads();
    int pc = 0;
    if (threadIdx.x < BQ) { pc = (cnt[threadIdx.x] + 7) & ~7; lofs[threadIdx.x] = pc; }
    __syncthreads();
    for (int off = 1; off < BQ; off <<= 1) {
        int t = 0;
        if (threadIdx.x < BQ && threadIdx.x >= off) t = lofs[threadIdx.x - off];
        __syncthreads();
        if (threadIdx.x < BQ) lofs[threadIdx.x] += t;   // inclusive over padded counts
        __syncthreads();
    }
    if (threadIdx.x < BQ) {
        int node = q * BQ + threadIdx.x;
        if (node < N_NODES) {
            int st = lofs[threadIdx.x] - pc;
            rs[node] = pbase + st;
            deg[node] = cnt[threadIdx.x];
            for (int i = cnt[threadIdx.x]; i < pc; ++i)
                perm[pbase + st + i] = N_NODES;          // pad -> zero row
        }
    }
    __syncthreads();
    for (int p = threadIdx.x; p < m; p += 1024) {
        unsigned w = tmp[beg + p];
        int dl = w >> 17;
        int s = w & 0x1FFFF;
        int r = atomicAdd(&fill[dl], 1);
        int st = lofs[dl] - ((cnt[dl] + 7) & ~7);
        perm[pbase + st + r] = s;
    }
}

// ---------------- transforms ----------------

// y1(half) = x @ W1l ; s1(f32) = x @ W1r + b1      (64 -> 16)
__global__ void k_t1(const float* __restrict__ x, const float* __restrict__ W1l,
                     const float* __restrict__ W1r, const float* __restrict__ b1,
                     __half* __restrict__ y1, float* __restrict__ s1, int n) {
    __shared__ float wl[64 * 16], wr[64 * 16], bb[16];
    for (int i = threadIdx.x; i < 64 * 16; i += blockDim.x) { wl[i] = W1l[i]; wr[i] = W1r[i]; }
    if (threadIdx.x < 16) bb[threadIdx.x] = b1[threadIdx.x];
    __syncthreads();
    int node = blockIdx.x * blockDim.x + threadIdx.x;
    if (node >= n) return;
    const float4* xr = reinterpret_cast<const float4*>(x + (size_t)node * 64);
    float accl[16], accr[16];
#pragma unroll
    for (int j = 0; j < 16; ++j) { accl[j] = 0.f; accr[j] = 0.f; }
#pragma unroll
    for (int q = 0; q < 16; ++q) {
        float4 v = xr[q];
        float xs[4] = {v.x, v.y, v.z, v.w};
#pragma unroll
        for (int u = 0; u < 4; ++u) {
            int k = q * 4 + u;
            float xv = xs[u];
#pragma unroll
            for (int j = 0; j < 16; ++j) {
                accl[j] += xv * wl[k * 16 + j];
                accr[j] += xv * wr[k * 16 + j];
            }
        }
    }
    alignas(16) __half yh[16];
#pragma unroll
    for (int j = 0; j < 16; ++j) yh[j] = __float2half(accl[j]);
    uint4* y4 = reinterpret_cast<uint4*>(y1 + (size_t)node * 16);
    const uint4* yv = reinterpret_cast<const uint4*>(yh);
    y4[0] = yv[0]; y4[1] = yv[1];
    float4* s4 = reinterpret_cast<float4*>(s1 + (size_t)node * 16);
#pragma unroll
    for (int q = 0; q < 4; ++q)
        s4[q] = make_float4(accr[q*4+0] + bb[q*4+0], accr[q*4+1] + bb[q*4+1],
                            accr[q*4+2] + bb[q*4+2], accr[q*4+3] + bb[q*4+3]);
}

// h2(f32) = mean2 @ W2l + h(half) @ W2r + b2      (16 -> 32)
__global__ void k_t2(const float* __restrict__ mean2, const __half* __restrict__ h,
                     const float* __restrict__ W2l, const float* __restrict__ W2r,
                     const float* __restrict__ b2, float* __restrict__ h2, int n) {
    __shared__ float wl[16 * 32], wr[16 * 32], bb[32];
    for (int i = threadIdx.x; i < 16 * 32; i += blockDim.x) { wl[i] = W2l[i]; wr[i] = W2r[i]; }
    if (threadIdx.x < 32) bb[threadIdx.x] = b2[threadIdx.x];
    __syncthreads();
    int node = blockIdx.x * blockDim.x + threadIdx.x;
    if (node >= n) return;
    float m[16], hh[16];
    const float4* m4 = reinterpret_cast<const float4*>(mean2 + (size_t)node * 16);
#pragma unroll
    for (int q = 0; q < 4; ++q) {
        float4 a = m4[q];
        m[q*4+0]=a.x; m[q*4+1]=a.y; m[q*4+2]=a.z; m[q*4+3]=a.w;
    }
    alignas(16) __half hv[16];
    const uint4* hp = reinterpret_cast<const uint4*>(h + (size_t)node * 16);
    uint4* hvp = reinterpret_cast<uint4*>(hv);
    hvp[0] = hp[0]; hvp[1] = hp[1];
#pragma unroll
    for (int k = 0; k < 16; ++k) hh[k] = __half2float(hv[k]);
    float acc[32];
#pragma unroll
    for (int j = 0; j < 32; ++j) acc[j] = bb[j];
#pragma unroll
    for (int k = 0; k < 16; ++k) {
#pragma unroll
        for (int j = 0; j < 32; ++j)
            acc[j] += m[k] * wl[k * 32 + j] + hh[k] * wr[k * 32 + j];
    }
    float4* o4 = reinterpret_cast<float4*>(h2 + (size_t)node * 32);
#pragma unroll
    for (int q = 0; q < 8; ++q)
        o4[q] = make_float4(acc[q*4+0], acc[q*4+1], acc[q*4+2], acc[q*4+3]);
}

// z = relu(h2); y3(half, stride 24) = z @ W3l ; s3(f32, stride 24) = z @ W3r + b3
__global__ void k_t3(const float* __restrict__ h2, const float* __restrict__ W3l,
                     const float* __restrict__ W3r, const float* __restrict__ b3,
                     __half* __restrict__ y3, float* __restrict__ s3, int n) {
    __shared__ float wl[32 * 21], wr[32 * 21], bb[21];
    for (int i = threadIdx.x; i < 32 * 21; i += blockDim.x) { wl[i] = W3l[i]; wr[i] = W3r[i]; }
    if (threadIdx.x < 21) bb[threadIdx.x] = b3[threadIdx.x];
    __syncthreads();
    int node = blockIdx.x * blockDim.x + threadIdx.x;
    if (node >= n) return;
    float z[32];
    const float4* h4 = reinterpret_cast<const float4*>(h2 + (size_t)node * 32);
#pragma unroll
    for (int q = 0; q < 8; ++q) {
        float4 v = h4[q];
        z[q*4+0] = fmaxf(v.x, 0.f); z[q*4+1] = fmaxf(v.y, 0.f);
        z[q*4+2] = fmaxf(v.z, 0.f); z[q*4+3] = fmaxf(v.w, 0.f);
    }
    float a[21], c[21];
#pragma unroll
    for (int j = 0; j < 21; ++j) { a[j] = 0.f; c[j] = bb[j]; }
#pragma unroll
    for (int k = 0; k < 32; ++k) {
#pragma unroll
        for (int j = 0; j < 21; ++j) {
            a[j] += z[k] * wl[k * 21 + j];
            c[j] += z[k] * wr[k * 21 + j];
        }
    }
    alignas(16) __half yh[24];
#pragma unroll
    for (int j = 0; j < 21; ++j) yh[j] = __float2half(a[j]);
    yh[21] = __half(0.f); yh[22] = __half(0.f); yh[23] = __half(0.f);
    uint4* yp = reinterpret_cast<uint4*>(y3 + (size_t)node * 24);
    const uint4* yv = reinterpret_cast<const uint4*>(yh);
    yp[0] = yv[0]; yp[1] = yv[1]; yp[2] = yv[2];
    float* so = s3 + (size_t)node * 24;
#pragma unroll
    for (int j = 0; j < 21; ++j) so[j] = c[j];
    so[21] = 0.f; so[22] = 0.f; so[23] = 0.f;
}

// ---- aggregation: padded segments, int4 perm loads, 8B-lane gathers ----

__device__ __forceinline__ void acc4(uint2 v, float& a0, float& a1, float& a2, float& a3) {
    __half2 lo = *reinterpret_cast<__half2*>(&v.x);
    __half2 hi = *reinterpret_cast<__half2*>(&v.y);
    float2 flo = __half22float2(lo), fhi = __half22float2(hi);
    a0 += flo.x; a1 += flo.y; a2 += fhi.x; a3 += fhi.y;
}

// layers 1-2: 4 lanes/node, each lane covers 4 features (uint2 = 4 halfs)
template <bool RELU, bool SELF, bool OUT_HALF>
__global__ void k_agg16(const uint2* __restrict__ y, const int* __restrict__ rs,
                        const int* __restrict__ deg, const int* __restrict__ perm,
                        const float* __restrict__ self, void* __restrict__ outp,
                        int n_nodes) {
    int t = blockIdx.x * blockDim.x + threadIdx.x;
    int node = t >> 2;
    int f = t & 3;
    if (node >= n_nodes) return;
    int beg = rs[node];
    int d = deg[node];
    int pend = beg + ((d + 7) & ~7);
    float a0 = 0.f, a1 = 0.f, a2 = 0.f, a3 = 0.f;
    for (int e = beg; e < pend; e += 8) {
        const int4* pp = reinterpret_cast<const int4*>(perm + e);
        int4 p0 = pp[0];
        int4 p1 = pp[1];
        uint2 v0 = y[(size_t)p0.x * 4 + f];
        uint2 v1 = y[(size_t)p0.y * 4 + f];
        uint2 v2 = y[(size_t)p0.z * 4 + f];
        uint2 v3 = y[(size_t)p0.w * 4 + f];
        uint2 v4 = y[(size_t)p1.x * 4 + f];
        uint2 v5 = y[(size_t)p1.y * 4 + f];
        uint2 v6 = y[(size_t)p1.z * 4 + f];
        uint2 v7 = y[(size_t)p1.w * 4 + f];
        acc4(v0, a0, a1, a2, a3); acc4(v1, a0, a1, a2, a3);
        acc4(v2, a0, a1, a2, a3); acc4(v3, a0, a1, a2, a3);
        acc4(v4, a0, a1, a2, a3); acc4(v5, a0, a1, a2, a3);
        acc4(v6, a0, a1, a2, a3); acc4(v7, a0, a1, a2, a3);
    }
    float inv = 1.0f / fmaxf((float)d, 1.0f);
    a0 *= inv; a1 *= inv; a2 *= inv; a3 *= inv;
    if (SELF) {
        float4 sv = *reinterpret_cast<const float4*>(self + (size_t)node * 16 + f * 4);
        a0 += sv.x; a1 += sv.y; a2 += sv.z; a3 += sv.w;
    }
    if (RELU) {
        a0 = fmaxf(a0, 0.f); a1 = fmaxf(a1, 0.f);
        a2 = fmaxf(a2, 0.f); a3 = fmaxf(a3, 0.f);
    }
    if constexpr (OUT_HALF) {
        __half2 p01 = __floats2half2_rn(a0, a1);
        __half2 p23 = __floats2half2_rn(a2, a3);
        uint2 o;
        o.x = *reinterpret_cast<unsigned*>(&p01);
        o.y = *reinterpret_cast<unsigned*>(&p23);
        ((uint2*)outp)[(size_t)node * 4 + f] = o;
    } else {
        ((float4*)outp)[(size_t)node * 4 + f] = make_float4(a0, a1, a2, a3);
    }
}

// layer 3: 6 lanes/node over stride-24 half table; self stride 24; out stride 21
__global__ void k_agg21(const uint2* __restrict__ y, const int* __restrict__ rs,
                        const int* __restrict__ deg, const int* __restrict__ perm,
                        const float* __restrict__ self24, float* __restrict__ outp,
                        int n_nodes) {
    int t = blockIdx.x * blockDim.x + threadIdx.x;
    int node = t / 6;
    int f = t - node * 6;
    if (node >= n_nodes) return;
    int beg = rs[node];
    int d = deg[node];
    int pend = beg + ((d + 7) & ~7);
    float a0 = 0.f, a1 = 0.f, a2 = 0.f, a3 = 0.f;
    for (int e = beg; e < pend; e += 8) {
        const int4* pp = reinterpret_cast<const int4*>(perm + e);
        int4 p0 = pp[0];
        int4 p1 = pp[1];
        uint2 v0 = y[(size_t)p0.x * 6 + f];
        uint2 v1 = y[(size_t)p0.y * 6 + f];
        uint2 v2 = y[(size_t)p0.z * 6 + f];
        uint2 v3 = y[(size_t)p0.w * 6 + f];
        uint2 v4 = y[(size_t)p1.x * 6 + f];
        uint2 v5 = y[(size_t)p1.y * 6 + f];
        uint2 v6 = y[(size_t)p1.z * 6 + f];
        uint2 v7 = y[(size_t)p1.w * 6 + f];
        acc4(v0, a0, a1, a2, a3); acc4(v1, a0, a1, a2, a3);
        acc4(v2, a0, a1, a2, a3); acc4(v3, a0, a1, a2, a3);
        acc4(v4, a0, a1, a2, a3); acc4(v5, a0, a1, a2, a3);
        acc4(v6, a0, a1, a2, a3); acc4(v7, a0, a1, a2, a3);
    }
    float inv = 1.0f / fmaxf((float)d, 1.0f);
    int c0 = f * 4;
    float4 sv = *reinterpret_cast<const float4*>(self24 + (size_t)node * 24 + c0);
    float r0 = a0 * inv + sv.x;
    float r1 = a1 * inv + sv.y;
    float r2 = a2 * inv + sv.z;
    float r3 = a3 * inv + sv.w;
    float* op = outp + (size_t)node * 21;
    op[c0] = r0;                      // c0 in {0,4,8,12,16,20}, always < 21
    if (c0 + 1 < 21) op[c0 + 1] = r1;
    if (c0 + 2 < 21) op[c0 + 2] = r2;
    if (c0 + 3 < 21) op[c0 + 3] = r3;
}

// ---------------- pooling + classifier ----------------

__device__ __forceinline__ int lowerb(const int* a, int n, int key) {
    int lo = 0, hi = n;
    while (lo < hi) { int mid = (lo + hi) >> 1; if (a[mid] < key) lo = mid + 1; else hi = mid; }
    return lo;
}

__global__ void k_pool(const float* __restrict__ h2, const int* __restrict__ batch,
                       float* __restrict__ gsum, float* __restrict__ gcnt, int n) {
    int g = blockIdx.x / POOL_SLICES;
    int slice = blockIdx.x - g * POOL_SLICES;
    __shared__ int sbeg, send;
    if (threadIdx.x == 0) { sbeg = lowerb(batch, n, g); send = lowerb(batch, n, g + 1); }
    __syncthreads();
    int beg = sbeg, end = send;
    int f = threadIdx.x & 31;
    int r = threadIdx.x >> 5;   // 8 row-groups
    float acc = 0.f;
    for (int i = beg + slice * 8 + r; i < end; i += POOL_SLICES * 8)
        acc += h2[(size_t)i * 32 + f];
    __shared__ float red[256];
    red[threadIdx.x] = acc;
    __syncthreads();
    if (r == 0) {
        float s = 0.f;
#pragma unroll
        for (int q = 0; q < 8; ++q) s += red[q * 32 + f];
        atomicAdd(&gsum[g * 32 + f], s);
    }
    if (slice == 0 && threadIdx.x == 0) gcnt[g] = (float)(end - beg);
}

__global__ void k_cls(const float* __restrict__ gsum, const float* __restrict__ gcnt,
                      const float* __restrict__ Wc, const float* __restrict__ bc,
                      float* __restrict__ outp) {
    int t = threadIdx.x;
    if (t >= N_GRAPHS * 10) return;
    int g = t / 10, c = t - g * 10;
    float cv = fmaxf(gcnt[g], 1.f);
    float acc = bc[c];
#pragma unroll
    for (int k = 0; k < 32; ++k) acc += (gsum[g * 32 + k] / cv) * Wc[k * 10 + c];
    outp[g * 10 + c] = acc;
}

// ---------------- launch ----------------

extern "C" void kernel_launch(void* const* d_in, const int* in_sizes, int n_in,
                              void* d_out, int out_size, void* d_ws, size_t ws_size,
                              hipStream_t stream) {
    const float* x    = (const float*)d_in[0];
    const int*   ei   = (const int*)d_in[1];
    const int*   batch= (const int*)d_in[2];
    const float* W1l  = (const float*)d_in[3];
    const float* b1   = (const float*)d_in[4];
    const float* W1r  = (const float*)d_in[5];
    const float* W2l  = (const float*)d_in[6];
    const float* b2   = (const float*)d_in[7];
    const float* W2r  = (const float*)d_in[8];
    const float* W3l  = (const float*)d_in[9];
    const float* b3   = (const float*)d_in[10];
    const float* W3r  = (const float*)d_in[11];
    const float* Wc   = (const float*)d_in[12];
    const float* bc   = (const float*)d_in[13];
    float* out = (float*)d_out;

    char* ws = (char*)d_ws;
    size_t off = 0;
    auto alloc = [&](size_t bytes) { size_t o = off; off += (bytes + 255) & ~(size_t)255; return o; };

    int*    rs    = (int*)(ws + alloc((size_t)N_NODES * 4));
    int*    deg   = (int*)(ws + alloc((size_t)N_NODES * 4));
    int*    perm  = (int*)(ws + alloc((size_t)(N_EDGES + (size_t)NBUCK * PADB + 64) * 4));
    int*    gh    = (int*)(ws + alloc((size_t)NBUCK * NBLK * 4));
    int*    btotal= (int*)(ws + alloc(256 * 4));
    int*    bstart= (int*)(ws + alloc(260 * 4));
    __half* y1    = (__half*)(ws + alloc((size_t)(N_NODES + 1) * 16 * 2));
    float*  s1    = (float*)(ws + alloc((size_t)N_NODES * 16 * 4));
    __half* h     = (__half*)(ws + alloc((size_t)(N_NODES + 1) * 16 * 2));
    float*  mean2 = (float*)(ws + alloc((size_t)N_NODES * 16 * 4));
    float*  h2    = (float*)(ws + alloc((size_t)N_NODES * 32 * 4));
    __half* y3    = (__half*)(ws + alloc((size_t)(N_NODES + 1) * 24 * 2));
    float*  s3    = (float*)(ws + alloc((size_t)N_NODES * 24 * 4));
    float*  gsum  = (float*)(ws + alloc((size_t)N_GRAPHS * 32 * 4));
    float*  gcnt  = (float*)(ws + alloc((size_t)N_GRAPHS * 4));

    // tmp (12.8 MB) aliases h2 (12.8 MB): tmp dead before k_t2 writes h2
    unsigned* tmp = (unsigned*)h2;

    const int* src = ei;
    const int* dst = ei + N_EDGES;

    int nb  = (N_NODES + 255) / 256;                 // 391
    int g4  = (N_NODES * 4 + 255) / 256;             // 1563
    int g6  = (N_NODES * 6 + 255) / 256;             // 2344

    // zero rows (gather target for pad entries), zero gsum
    (void)hipMemsetAsync(y1 + (size_t)N_NODES * 16, 0, 32, stream);
    (void)hipMemsetAsync(h  + (size_t)N_NODES * 16, 0, 32, stream);
    (void)hipMemsetAsync(y3 + (size_t)N_NODES * 24, 0, 48, stream);
    (void)hipMemsetAsync(gsum, 0, (size_t)N_GRAPHS * 32 * 4, stream);

    // CSR build (bucketed 2-pass counting sort, 8-padded per-node segments)
    kp1_hist   <<<NBLK, 256, 0, stream>>>(dst, gh, N_EDGES);
    kp1_scanA  <<<NBUCK, 256, 0, stream>>>(gh, btotal);
    kp1_scanB  <<<1, 256, 0, stream>>>(btotal, bstart);
    kp1_scatter<<<NBLK, 256, 0, stream>>>(src, dst, gh, bstart, tmp, N_EDGES);
    kp2        <<<NBUCK, 1024, 0, stream>>>(tmp, bstart, rs, deg, perm);

    // layer 1: transform-first (64->16); aggregate (+self +relu) -> h (fp16)
    k_t1<<<nb, 256, 0, stream>>>(x, W1l, W1r, b1, y1, s1, N_NODES);
    k_agg16<true, true, true><<<g4, 256, 0, stream>>>(
        (const uint2*)y1, rs, deg, perm, s1, h, N_NODES);

    // layer 2: aggregate-first -> mean2 (f32), then 16->32
    k_agg16<false, false, false><<<g4, 256, 0, stream>>>(
        (const uint2*)h, rs, deg, perm, nullptr, mean2, N_NODES);
    k_t2<<<nb, 256, 0, stream>>>(mean2, h, W2l, W2r, b2, h2, N_NODES);

    // layer 3: transform-first on relu(h2) (32->21); aggregate, +self
    k_t3<<<nb, 256, 0, stream>>>(h2, W3l, W3r, b3, y3, s3, N_NODES);
    k_agg21<<<g6, 256, 0, stream>>>(
        (const uint2*)y3, rs, deg, perm, s3, out + N_GRAPHS * 10, N_NODES);

    // pooling over h2 (pre-relu) + classifier
    k_pool<<<N_GRAPHS * POOL_SLICES, 256, 0, stream>>>(h2, batch, gsum, gcnt, N_NODES);
    k_cls<<<1, 640, 0, stream>>>(gsum, gcnt, Wc, bc, out);
}